// Round 11
// baseline (482.196 us; speedup 1.0000x reference)
//
#include <hip/hip_runtime.h>
#include <math.h>

#define D 512
#define M 128
#define B 16
#define KSEL 4
#define NC 2048           // M*B
#define NTOK 4096         // 2*2048

typedef unsigned short ushort;
typedef unsigned int uint;
typedef unsigned long long u64;
typedef __attribute__((ext_vector_type(8))) short short8;   // 8 bf16 (4 VGPRs)
typedef __attribute__((ext_vector_type(4))) float floatx4;  // 4 fp32 acc

// ws layout (float indices)
#define WS_EACC   0       // [128]
#define WS_CACC   128     // [128]
#define WS_VSUM   256     // [1]
#define WS_USUM   257     // [1]
#define WS_CNT_I  258     // int counters [128] (inside zeroed first 512 floats)
#define WS_RCNT_I 386     // int recheck counter (inside zeroed head)
#define WS_VSCALE 512     // [2048] 1/||V col||
#define WS_USCALE 2560    // [2048] tanh(us)/||U col||
#define WS_E_F    4608    // [NTOK*M] fp32 energies, 2 MB
#define WS_RBF_F  528896  // R bf16 [NTOK][NC] (16 MB)
#define WS_XH_F   2626048 // xh bf16 [NTOK][D]; REUSED as contrib after mfma_fused
#define WS_XL_F   3674624 // xl bf16
#define WS_VHT_F  4723200 // VhT bf16 [NC][D]
#define WS_VLT_F  5247488
#define WS_UHT_F  5771776 // UhT bf16 [NC][D] (col = m*16+b)
#define WS_ULT_F  6296064
#define WS_LIST_F 6820352 // int [128][4096] per-expert token lists, packed (t<<2)|k
#define WS_RLIST_F 7344640 // int [4096] recheck token list
                           // end: 7348736 floats = 29.4 MB (ws >= 35.7 MB proven)

// out layout (floats)
#define OUT_TE   2097152
#define OUT_EPE  2097153
#define OUT_RE   2097281
#define OUT_SR   2097409
#define OUT_VPEN 2097537
#define OUT_UPEN 2097538
#define OUT_AUX  2097539

#define GLDS16(g, l) __builtin_amdgcn_global_load_lds(                        \
    (const __attribute__((address_space(1))) unsigned int*)(g),               \
    (__attribute__((address_space(3))) unsigned int*)(l), 16, 0, 0)

__device__ __forceinline__ ushort f2bf(float f) {   // RNE
    union { float f; uint u; } a; a.f = f;
    uint u = a.u;
    u += 0x7fffu + ((u >> 16) & 1u);
    return (ushort)(u >> 16);
}
__device__ __forceinline__ float bf2f(ushort h) {
    union { uint u; float f; } a; a.u = ((uint)h) << 16;
    return a.f;
}

// ---------------- fused prep: converts + scales + ws-zero (1570 blocks) ----
__launch_bounds__(256)
__global__ void prep_kernel(const float* __restrict__ x, const float* __restrict__ V,
                            const float* __restrict__ U, const float* __restrict__ us_in,
                            ushort* __restrict__ xh, ushort* __restrict__ xl,
                            ushort* __restrict__ vht, ushort* __restrict__ vlt,
                            ushort* __restrict__ uht, ushort* __restrict__ ult,
                            float* __restrict__ ws) {
    __shared__ float ts[64][65];
    const int bid = blockIdx.x;
    const int tid = threadIdx.x;

    if (bid < 1024) {                       // convert_x
        const int idx = (bid * 256 + tid) * 8;
        float4 v0 = *(const float4*)(x + idx);
        float4 v1 = *(const float4*)(x + idx + 4);
        float vv[8] = {v0.x, v0.y, v0.z, v0.w, v1.x, v1.y, v1.z, v1.w};
        union { ushort u[8]; uint4 q; } H, L;
#pragma unroll
        for (int j = 0; j < 8; ++j) {
            ushort h = f2bf(vv[j]);
            H.u[j] = h;
            L.u[j] = f2bf(vv[j] - bf2f(h));
        }
        *(uint4*)(xh + idx) = H.q;
        *(uint4*)(xl + idx) = L.q;
    } else if (bid < 1280) {                // convert_VT (64x64 tile transpose)
        const int vb = bid - 1024;
        const int col0 = (vb & 31) * 64;
        const int d0 = (vb >> 5) * 64;
#pragma unroll
        for (int i = 0; i < 16; ++i) {
            int idx = i * 256 + tid;
            int r = idx >> 6, c = idx & 63;
            ts[r][c] = V[(size_t)(d0 + r) * NC + col0 + c];
        }
        __syncthreads();
#pragma unroll
        for (int i = 0; i < 16; ++i) {
            int idx = i * 256 + tid;
            int c2 = idx >> 6, d2 = idx & 63;
            float v = ts[d2][c2];
            ushort h = f2bf(v);
            vht[(size_t)(col0 + c2) * D + d0 + d2] = h;
            vlt[(size_t)(col0 + c2) * D + d0 + d2] = f2bf(v - bf2f(h));
        }
    } else if (bid < 1408) {                // convert_UT (one expert per block)
        const int m = bid - 1280;
        float (*t2)[129] = (float (*)[129])ts;   // 16 x 129 view
        for (int d0 = 0; d0 < D; d0 += 128) {
            __syncthreads();
#pragma unroll
            for (int i = 0; i < 8; ++i) {
                int idx = i * 256 + tid;
                int d2 = idx >> 4, b2 = idx & 15;
                t2[b2][d2] = U[(size_t)m * (D * B) + (size_t)(d0 + d2) * B + b2];
            }
            __syncthreads();
#pragma unroll
            for (int i = 0; i < 8; ++i) {
                int idx = i * 256 + tid;
                int b3 = idx >> 7, d3 = idx & 127;
                float v = t2[b3][d3];
                ushort h = f2bf(v);
                uht[(size_t)((m << 4) + b3) * D + d0 + d3] = h;
                ult[(size_t)((m << 4) + b3) * D + d0 + d3] = f2bf(v - bf2f(h));
            }
        }
    } else {                                // scales + ws-head zero
        const int bx = bid - 1408;
        if (bx >= 160) {
            ws[(bx - 160) * 256 + tid] = 0.0f;
            return;
        }
        if (bx < 32) {
            const int c = bx * 64 + (tid & 63);
            const int dg = tid >> 6;
            float s = 0.0f;
            for (int d = dg; d < D; d += 4) {
                float v = V[(size_t)d * NC + c];
                s = fmaf(v, v, s);
            }
            float (*sh)[64] = (float (*)[64])ts;
            sh[dg][tid & 63] = s;
            __syncthreads();
            if (tid < 64) {
                float t = (sh[0][tid] + sh[1][tid]) + (sh[2][tid] + sh[3][tid]);
                ws[WS_VSCALE + bx * 64 + tid] = 1.0f / sqrtf(t);
            }
        } else {
            const int m = bx - 32;
            const float* p = U + (size_t)m * (D * B);
            float s = 0.0f;
            for (int i = tid; i < D * B; i += 256) {
                float v = p[i];
                s = fmaf(v, v, s);
            }
            float* sh2 = &ts[0][0];
            sh2[tid] = s;
            __syncthreads();
            if (tid < 16) {
                float t = 0.0f;
#pragma unroll
                for (int j = 0; j < 16; ++j) t += sh2[tid + (j << 4)];
                ws[WS_USCALE + (m << 4) + tid] = tanhf(us_in[(m << 4) + tid]) / sqrtf(t);
            }
        }
    }
}

// ---------------- fused MFMA: gemm tiles (blocks 0..511) + gram tiles (512..783)
// (exact round-9 structure: 3-pass split-bf16 for both paths)
__launch_bounds__(256)
__global__ void mfma_fused(const ushort* __restrict__ xh, const ushort* __restrict__ xl,
                           const ushort* __restrict__ vht, const ushort* __restrict__ vlt,
                           const ushort* __restrict__ uht, const ushort* __restrict__ ult,
                           float* __restrict__ ws, ushort* __restrict__ rbf) {
    __shared__ ushort smem[32768];   // 2 bufs x 4 tiles x (128 rows x 32 bf16)
    const int bid = blockIdx.x;
    const int tid = threadIdx.x, lane = tid & 63, w = tid >> 6;
    const int wr = w >> 1, wc = w & 1;
    const int r15 = lane & 15, q = lane >> 4;
    const int srl = lane >> 2;
    const int skq = (lane & 3) ^ ((lane >> 3) & 3);
    const int perm8 = (q ^ ((r15 >> 1) & 3)) * 8;

    const int is_gemm = bid < 512;
    const ushort* srcs[4];
    int rbase[4];
    int gi = 0, gj = 0, which = 0;
    if (is_gemm) {
        const int tokB = (bid & 31) * 128, colB = (bid >> 5) * 128;
        srcs[0] = xh; srcs[1] = xl; srcs[2] = vht; srcs[3] = vlt;
        rbase[0] = tokB; rbase[1] = tokB; rbase[2] = colB; rbase[3] = colB;
    } else {
        int t = bid - 512;
        which = t >= 136;
        if (which) t -= 136;
        int bi = 0, rem = 16;
        while (t >= rem) { t -= rem; --rem; ++bi; }
        gi = bi; gj = bi + t;
        const ushort* ht = which ? uht : vht;
        const ushort* lt = which ? ult : vlt;
        srcs[0] = ht; srcs[1] = lt; srcs[2] = ht; srcs[3] = lt;
        rbase[0] = gi * 128; rbase[1] = gi * 128; rbase[2] = gj * 128; rbase[3] = gj * 128;
    }

    floatx4 acc[4][4];
#pragma unroll
    for (int i = 0; i < 4; ++i)
#pragma unroll
        for (int j = 0; j < 4; ++j) acc[i][j] = (floatx4){0.f, 0.f, 0.f, 0.f};

    auto stage = [&](int buf, int c) {
        const int kb = c * 32 + skq * 8;
#pragma unroll
        for (int tI = 0; tI < 4; ++tI) {
            const ushort* s = srcs[tI] + (size_t)rbase[tI] * D + kb;
#pragma unroll
            for (int sub = 0; sub < 2; ++sub) {
                const int row16 = w * 32 + sub * 16;
                GLDS16(s + (size_t)(row16 + srl) * D,
                       &smem[buf * 16384 + tI * 4096 + row16 * 32]);
            }
        }
    };

    stage(0, 0);
    for (int c = 0; c < 16; ++c) {
        __syncthreads();
        if (c < 15) stage((c + 1) & 1, c + 1);
        const ushort* bp = &smem[(c & 1) * 16384];
        short8 ah[4], al[4], bh[4], bl[4];
#pragma unroll
        for (int s = 0; s < 4; ++s) {
            const int ra = (wr * 64 + s * 16 + r15) * 32 + perm8;
            ah[s] = *(const short8*)&bp[ra];
            al[s] = *(const short8*)&bp[4096 + ra];
            const int rb = (wc * 64 + s * 16 + r15) * 32 + perm8;
            bh[s] = *(const short8*)&bp[8192 + rb];
            bl[s] = *(const short8*)&bp[12288 + rb];
        }
#pragma unroll
        for (int st = 0; st < 4; ++st)
#pragma unroll
            for (int sc = 0; sc < 4; ++sc) {
                acc[st][sc] = __builtin_amdgcn_mfma_f32_16x16x32_bf16(ah[st], bh[sc], acc[st][sc], 0, 0, 0);
                acc[st][sc] = __builtin_amdgcn_mfma_f32_16x16x32_bf16(ah[st], bl[sc], acc[st][sc], 0, 0, 0);
                acc[st][sc] = __builtin_amdgcn_mfma_f32_16x16x32_bf16(al[st], bh[sc], acc[st][sc], 0, 0, 0);
            }
    }

    if (is_gemm) {
        const int tok0 = (bid & 31) * 128 + wr * 64, col0 = (bid >> 5) * 128 + wc * 64;
#pragma unroll
        for (int sc = 0; sc < 4; ++sc) {
            const int colg = col0 + sc * 16 + r15;
            const float vs = ws[WS_VSCALE + colg];
            const int ex = colg >> 4;
#pragma unroll
            for (int st = 0; st < 4; ++st) {
                const int rowb = tok0 + st * 16 + q * 4;
                float r0 = acc[st][sc][0] * vs;
                float r1 = acc[st][sc][1] * vs;
                float r2 = acc[st][sc][2] * vs;
                float r3 = acc[st][sc][3] * vs;
                rbf[(size_t)(rowb + 0) * NC + colg] = f2bf(r0);
                rbf[(size_t)(rowb + 1) * NC + colg] = f2bf(r1);
                rbf[(size_t)(rowb + 2) * NC + colg] = f2bf(r2);
                rbf[(size_t)(rowb + 3) * NC + colg] = f2bf(r3);
                float e0 = r0 * r0, e1 = r1 * r1, e2 = r2 * r2, e3 = r3 * r3;
#pragma unroll
                for (int mk = 1; mk < 16; mk <<= 1) {
                    e0 += __shfl_xor(e0, mk);
                    e1 += __shfl_xor(e1, mk);
                    e2 += __shfl_xor(e2, mk);
                    e3 += __shfl_xor(e3, mk);
                }
                if (r15 == 0) {
                    float* ep = ws + WS_E_F + (size_t)rowb * M + ex;
                    ep[0] = e0; ep[M] = e1; ep[2 * M] = e2; ep[3 * M] = e3;
                }
            }
        }
    } else {
        const float* scl = ws + (which ? WS_USCALE : WS_VSCALE);
        float* sum_out = ws + (which ? WS_USUM : WS_VSUM);
        float local = 0.0f;
#pragma unroll
        for (int sc = 0; sc < 4; ++sc) {
            const int colg = gj * 128 + wc * 64 + sc * 16 + r15;
            const float scj = scl[colg];
#pragma unroll
            for (int st = 0; st < 4; ++st) {
#pragma unroll
                for (int reg = 0; reg < 4; ++reg) {
                    const int rowg = gi * 128 + wr * 64 + st * 16 + q * 4 + reg;
                    float g = acc[st][sc][reg] * scl[rowg] * scj;
                    if (rowg == colg) g -= 1.0f;
                    local += fabsf(g);
                }
            }
        }
        if (gi < gj) local *= 2.0f;
#pragma unroll
        for (int mk = 1; mk < 64; mk <<= 1) local += __shfl_xor(local, mk);
        __shared__ float red[4];
        if (lane == 0) red[w] = local;
        __syncthreads();
        if (tid == 0) atomicAdd(sum_out, (red[0] + red[1]) + (red[2] + red[3]));
    }
}

// Wave-per-token top-4 with robustness gate: u64-key butterfly gives the exact
// sorted top-4 (jax tie order); a masked max-butterfly gives the 5th. If the
// 4/5 relative gap > 1e-3 (>>300x our split-bf16 E error) the selection is
// provably exact -> finalize. Otherwise defer to fp64 recheck.
__launch_bounds__(256)
__global__ void topk_kernel(float* __restrict__ ws) {
    const int tid = threadIdx.x, lane = tid & 63, w = tid >> 6;
    const int t = blockIdx.x * 4 + w;
    int* icnt = (int*)ws + WS_CNT_I;
    int* ilist = (int*)(ws + WS_LIST_F);

    const float2 ev = *(const float2*)(ws + WS_E_F + (size_t)t * M + lane * 2);
    const uint i0 = (uint)(lane * 2), i1 = i0 + 1;
    u64 k0 = ((u64)__float_as_uint(ev.x) << 32) | (uint)(~i0);
    u64 k1 = ((u64)__float_as_uint(ev.y) << 32) | (uint)(~i1);
    u64 s0 = k0 > k1 ? k0 : k1;
    u64 s1 = k0 > k1 ? k1 : k0;
    u64 s2 = 0, s3 = 0;

#pragma unroll
    for (int mk = 1; mk < 64; mk <<= 1) {
        u64 o0 = __shfl_xor(s0, mk);
        u64 o1 = __shfl_xor(s1, mk);
        u64 o2 = __shfl_xor(s2, mk);
        u64 o3 = __shfl_xor(s3, mk);
        u64 c0 = s0 > o3 ? s0 : o3;
        u64 c1 = s1 > o2 ? s1 : o2;
        u64 c2 = s2 > o1 ? s2 : o1;
        u64 c3 = s3 > o0 ? s3 : o0;
        u64 d0 = c0 > c2 ? c0 : c2, d2 = c0 > c2 ? c2 : c0;
        u64 d1 = c1 > c3 ? c1 : c3, d3 = c1 > c3 ? c3 : c1;
        s0 = d0 > d1 ? d0 : d1; s1 = d0 > d1 ? d1 : d0;
        s2 = d2 > d3 ? d2 : d3; s3 = d2 > d3 ? d3 : d2;
    }
    // all lanes now hold the identical global sorted top-4 (s0..s3)

    // 5th best: mask this lane's keys if they are in the top-4, max-butterfly
    u64 m0 = (k0 == s0 || k0 == s1 || k0 == s2 || k0 == s3) ? 0 : k0;
    u64 m1 = (k1 == s0 || k1 == s1 || k1 == s2 || k1 == s3) ? 0 : k1;
    u64 mx = m0 > m1 ? m0 : m1;
#pragma unroll
    for (int mk = 1; mk < 64; mk <<= 1) {
        u64 om = __shfl_xor(mx, mk);
        if (om > mx) mx = om;
    }

    const float e4 = __uint_as_float((uint)(s3 >> 32));
    const float e5 = __uint_as_float((uint)(mx >> 32));
    const bool robust = (e4 - e5) > 1e-3f * e4;

    if (robust) {
        if (lane < 4) {
            u64 key = (lane == 0) ? s0 : (lane == 1) ? s1 : (lane == 2) ? s2 : s3;
            const int e = (int)(~(uint)key);
            const float val = __uint_as_float((uint)(key >> 32));
            atomicAdd(&ws[WS_EACC + e], val);
            atomicAdd(&ws[WS_CACC + e], 1.0f);
            int pos = atomicAdd(&icnt[e], 1);
            ilist[(e << 12) + pos] = (t << 2) | lane;
        }
    } else {
        if (lane == 0) {
            int* rc = (int*)ws + WS_RCNT_I;
            int p = atomicAdd(rc, 1);
            ((int*)(ws + WS_RLIST_F))[p] = t;
        }
    }
}

// fp64 exact re-selection for near-tie tokens (expected: a handful).
// E_true[e] = sum_b dot(x, V_col)^2 / ||V_col||^2 computed in fp64.
__launch_bounds__(256)
__global__ void recheck_kernel(const float* __restrict__ x,
                               const float* __restrict__ V,
                               float* __restrict__ ws) {
    const int rcnt = ((const int*)ws)[WS_RCNT_I];
    __shared__ double Esh[128];
    __shared__ float xs[512];
    const int tid = threadIdx.x;

    for (int ri = blockIdx.x; ri < rcnt; ri += gridDim.x) {
        const int t = ((const int*)(ws + WS_RLIST_F))[ri];
        if (tid < 128)
            *(float4*)&xs[tid * 4] = *(const float4*)(x + (size_t)t * D + tid * 4);
        __syncthreads();

        double dot[8] = {0, 0, 0, 0, 0, 0, 0, 0};
        double nrm[8] = {0, 0, 0, 0, 0, 0, 0, 0};
        for (int d = 0; d < D; ++d) {
            const double xv = (double)xs[d];
            const float* vp = V + (size_t)d * NC + tid * 8;
            float4 a = *(const float4*)vp, b = *(const float4*)(vp + 4);
            float vv[8] = {a.x, a.y, a.z, a.w, b.x, b.y, b.z, b.w};
#pragma unroll
            for (int j = 0; j < 8; ++j) {
                double v = (double)vv[j];
                dot[j] += xv * v;
                nrm[j] += v * v;
            }
        }
        double epart = 0.0;
#pragma unroll
        for (int j = 0; j < 8; ++j) epart += dot[j] * dot[j] / nrm[j];
        double other = __shfl_xor(epart, 1);
        if ((tid & 1) == 0) Esh[tid >> 1] = epart + other;
        __syncthreads();

        if (tid == 0) {
            double bv0 = -1.0, bv1 = -1.0, bv2 = -1.0, bv3 = -1.0;
            int bi0 = 0, bi1 = 0, bi2 = 0, bi3 = 0;
            for (int m = 0; m < M; ++m) {
                double v = Esh[m];
                if (v > bv3) {
                    if (v > bv0) {
                        bv3 = bv2; bi3 = bi2; bv2 = bv1; bi2 = bi1; bv1 = bv0; bi1 = bi0;
                        bv0 = v; bi0 = m;
                    } else if (v > bv1) {
                        bv3 = bv2; bi3 = bi2; bv2 = bv1; bi2 = bi1;
                        bv1 = v; bi1 = m;
                    } else if (v > bv2) {
                        bv3 = bv2; bi3 = bi2;
                        bv2 = v; bi2 = m;
                    } else {
                        bv3 = v; bi3 = m;
                    }
                }
            }
            int sel[4] = {bi0, bi1, bi2, bi3};
            int* icnt = (int*)ws + WS_CNT_I;
            int* ilist = (int*)(ws + WS_LIST_F);
#pragma unroll
            for (int k = 0; k < 4; ++k) {
                const int e = sel[k];
                const float evf = ws[WS_E_F + (size_t)t * M + e];
                atomicAdd(&ws[WS_EACC + e], evf);
                atomicAdd(&ws[WS_CACC + e], 1.0f);
                int pos = atomicAdd(&icnt[e], 1);
                ilist[(e << 12) + pos] = (t << 2) | k;
            }
        }
        __syncthreads();
    }
}

// Expert-major contributions: contrib[t][k][d] (bf16 pairs packed in uint).
__launch_bounds__(256)
__global__ void expert_contrib_kernel(const float* __restrict__ U,
                                      const ushort* __restrict__ rbf,
                                      const float* __restrict__ ws,
                                      uint* __restrict__ contrib) {
    const int e = blockIdx.x;
    const int tid = threadIdx.x;
    const int cnt = ((const int*)ws)[WS_CNT_I + e];
    if ((int)blockIdx.y >= cnt) return;

    float usc[16];
#pragma unroll
    for (int b = 0; b < 16; ++b) usc[b] = ws[WS_USCALE + (e << 4) + b];

    const float* Up = U + (size_t)e * (D * B);
    float u0[16], u1[16];
#pragma unroll
    for (int qd = 0; qd < 4; ++qd) {
        float4 a = *(const float4*)(Up + (size_t)(2 * tid) * B + qd * 4);
        float4 b4 = *(const float4*)(Up + (size_t)(2 * tid + 1) * B + qd * 4);
        u0[qd * 4 + 0] = a.x * usc[qd * 4 + 0];
        u0[qd * 4 + 1] = a.y * usc[qd * 4 + 1];
        u0[qd * 4 + 2] = a.z * usc[qd * 4 + 2];
        u0[qd * 4 + 3] = a.w * usc[qd * 4 + 3];
        u1[qd * 4 + 0] = b4.x * usc[qd * 4 + 0];
        u1[qd * 4 + 1] = b4.y * usc[qd * 4 + 1];
        u1[qd * 4 + 2] = b4.z * usc[qd * 4 + 2];
        u1[qd * 4 + 3] = b4.w * usc[qd * 4 + 3];
    }

    const int* ilist = (const int*)(ws + WS_LIST_F) + (e << 12);
    int i = blockIdx.y;
    int pk = (i < cnt) ? ilist[i] : 0;
    while (i < cnt) {
        const int t = pk >> 2, k = pk & 3;
        const ushort* rp = rbf + (size_t)t * NC + (e << 4);
        union { ushort u[16]; uint4 q[2]; } R;
        R.q[0] = *(const uint4*)(rp);
        R.q[1] = *(const uint4*)(rp + 8);
        const int inext = i + 4;
        if (inext < cnt) pk = ilist[inext];
        float acc0 = 0.0f, acc1 = 0.0f;
#pragma unroll
        for (int b = 0; b < 16; ++b) {
            const float wv = bf2f(R.u[b]);
            acc0 = fmaf(u0[b], wv, acc0);
            acc1 = fmaf(u1[b], wv, acc1);
        }
        contrib[(size_t)((t << 2) + k) * 256 + tid] =
            (uint)f2bf(acc0) | ((uint)f2bf(acc1) << 16);
        i = inext;
    }
}

// blocks 0..1023: out = x + sum_k contrib  ; block 1024: finalize scalars
__launch_bounds__(256)
__global__ void combine_kernel(const float* __restrict__ x,
                               const uint* __restrict__ contrib,
                               const float* __restrict__ ws,
                               float* __restrict__ out) {
    if (blockIdx.x == 1024) {               // finalize
        const int m = threadIdx.x;
        if (m >= 128) return;
        float e = ws[WS_EACC + m] * (1.0f / (float)NTOK);
        float c = ws[WS_CACC + m] * (1.0f / (float)NTOK);
        float s = e;
#pragma unroll
        for (int off = 32; off > 0; off >>= 1) s += __shfl_down(s, off);
        __shared__ float sh[2];
        if ((m & 63) == 0) sh[m >> 6] = s;
        __syncthreads();
        float total = sh[0] + sh[1];
        float total_energy = fmaxf(total, 1e-12f);
        out[OUT_EPE + m] = e;
        out[OUT_RE + m] = e / total_energy;
        out[OUT_SR + m] = c;
        if (m == 0) {
            out[OUT_TE] = total_energy;
            float inv_n2 = 1.0f / ((float)NC * (float)NC);
            float sqrtD = sqrtf((float)D);
            float vpen = ws[WS_VSUM] * inv_n2 * sqrtD;
            float upen = ws[WS_USUM] * inv_n2 * sqrtD;
            out[OUT_VPEN] = vpen;
            out[OUT_UPEN] = upen;
            out[OUT_AUX] = 0.01f * vpen - total_energy;
        }
        return;
    }

    const int gid = blockIdx.x * 256 + threadIdx.x;
    const int t = gid >> 6;
    const int dq = (gid & 63) << 3;
    const uint4* cp = (const uint4*)contrib;

    float s[8];
    float4 x0 = *(const float4*)(x + (size_t)t * D + dq);
    float4 x1 = *(const float4*)(x + (size_t)t * D + dq + 4);
    s[0] = x0.x; s[1] = x0.y; s[2] = x0.z; s[3] = x0.w;
    s[4] = x1.x; s[5] = x1.y; s[6] = x1.z; s[7] = x1.w;
#pragma unroll
    for (int k = 0; k < KSEL; ++k) {
        uint4 cvec = cp[(size_t)((t << 2) + k) * 64 + (dq >> 3)];
        uint cc[4] = {cvec.x, cvec.y, cvec.z, cvec.w};
#pragma unroll
        for (int j = 0; j < 4; ++j) {
            s[2 * j]     += bf2f((ushort)(cc[j] & 0xffffu));
            s[2 * j + 1] += bf2f((ushort)(cc[j] >> 16));
        }
    }
    float* op = out + (size_t)t * D + dq;
    *(float4*)(op)     = make_float4(s[0], s[1], s[2], s[3]);
    *(float4*)(op + 4) = make_float4(s[4], s[5], s[6], s[7]);
}

extern "C" void kernel_launch(void* const* d_in, const int* in_sizes, int n_in,
                              void* d_out, int out_size, void* d_ws, size_t ws_size,
                              hipStream_t stream) {
    const float* x  = (const float*)d_in[0];
    const float* V  = (const float*)d_in[1];
    const float* U  = (const float*)d_in[2];
    const float* us = (const float*)d_in[3];
    float* out = (float*)d_out;
    float* ws  = (float*)d_ws;

    ushort* xh  = (ushort*)(ws + WS_XH_F);
    ushort* xl  = (ushort*)(ws + WS_XL_F);
    ushort* vht = (ushort*)(ws + WS_VHT_F);
    ushort* vlt = (ushort*)(ws + WS_VLT_F);
    ushort* uht = (ushort*)(ws + WS_UHT_F);
    ushort* ult = (ushort*)(ws + WS_ULT_F);
    ushort* rbf = (ushort*)(ws + WS_RBF_F);
    uint* contrib = (uint*)(ws + WS_XH_F);   // reuses xh..ult after mfma_fused

    prep_kernel<<<1570, 256, 0, stream>>>(x, V, U, us, xh, xl, vht, vlt, uht, ult, ws);
    mfma_fused<<<784, 256, 0, stream>>>(xh, xl, vht, vlt, uht, ult, ws, rbf);
    topk_kernel<<<NTOK / 4, 256, 0, stream>>>(ws);
    recheck_kernel<<<64, 256, 0, stream>>>(x, V, ws);
    expert_contrib_kernel<<<dim3(128, 4), 256, 0, stream>>>(U, rbf, ws, contrib);
    combine_kernel<<<1025, 256, 0, stream>>>(x, contrib, ws, out);
}

// Round 12
// 268.289 us; speedup vs baseline: 1.7973x; 1.7973x over previous
//
#include <hip/hip_runtime.h>
#include <math.h>

#define D 512
#define M 128
#define B 16
#define KSEL 4
#define NC 2048           // M*B
#define NTOK 4096         // 2*2048

typedef unsigned short ushort;
typedef unsigned int uint;
typedef unsigned long long u64;
typedef __attribute__((ext_vector_type(8))) short short8;   // 8 bf16 (4 VGPRs)
typedef __attribute__((ext_vector_type(4))) float floatx4;  // 4 fp32 acc

// ws layout (float indices)
#define WS_EACC   0       // [128]
#define WS_CACC   128     // [128]
#define WS_VSUM   256     // [1]
#define WS_USUM   257     // [1]
#define WS_CNT_I  258     // int counters [128] (inside zeroed first 512 floats)
#define WS_RCNT_I 386     // int recheck counter (inside zeroed head)
#define WS_VSCALE 512     // [2048] 1/||V col||
#define WS_USCALE 2560    // [2048] tanh(us)/||U col||
#define WS_E_F    4608    // [NTOK*M] fp32 energies, 2 MB
#define WS_RBF_F  528896  // R bf16 [NTOK][NC] (16 MB)
#define WS_XH_F   2626048 // xh bf16 [NTOK][D]; REUSED as contrib after mfma_fused
#define WS_XL_F   3674624 // xl bf16
#define WS_VHT_F  4723200 // VhT bf16 [NC][D]
#define WS_VLT_F  5247488
#define WS_UHT_F  5771776 // UhT bf16 [NC][D] (col = m*16+b)
#define WS_ULT_F  6296064
#define WS_LIST_F 6820352 // int [128][4096] per-expert token lists, packed (t<<2)|k
#define WS_RLIST_F 7344640 // int [4096] recheck token list
                           // end: 7348736 floats = 29.4 MB (ws >= 35.7 MB proven)

// out layout (floats)
#define OUT_TE   2097152
#define OUT_EPE  2097153
#define OUT_RE   2097281
#define OUT_SR   2097409
#define OUT_VPEN 2097537
#define OUT_UPEN 2097538
#define OUT_AUX  2097539

#define GLDS16(g, l) __builtin_amdgcn_global_load_lds(                        \
    (const __attribute__((address_space(1))) unsigned int*)(g),               \
    (__attribute__((address_space(3))) unsigned int*)(l), 16, 0, 0)

__device__ __forceinline__ ushort f2bf(float f) {   // RNE
    union { float f; uint u; } a; a.f = f;
    uint u = a.u;
    u += 0x7fffu + ((u >> 16) & 1u);
    return (ushort)(u >> 16);
}
__device__ __forceinline__ float bf2f(ushort h) {
    union { uint u; float f; } a; a.u = ((uint)h) << 16;
    return a.f;
}

// ---------------- fused prep: converts + scales + ws-zero (1570 blocks) ----
__launch_bounds__(256)
__global__ void prep_kernel(const float* __restrict__ x, const float* __restrict__ V,
                            const float* __restrict__ U, const float* __restrict__ us_in,
                            ushort* __restrict__ xh, ushort* __restrict__ xl,
                            ushort* __restrict__ vht, ushort* __restrict__ vlt,
                            ushort* __restrict__ uht, ushort* __restrict__ ult,
                            float* __restrict__ ws) {
    __shared__ float ts[64][65];
    const int bid = blockIdx.x;
    const int tid = threadIdx.x;

    if (bid < 1024) {                       // convert_x
        const int idx = (bid * 256 + tid) * 8;
        float4 v0 = *(const float4*)(x + idx);
        float4 v1 = *(const float4*)(x + idx + 4);
        float vv[8] = {v0.x, v0.y, v0.z, v0.w, v1.x, v1.y, v1.z, v1.w};
        union { ushort u[8]; uint4 q; } H, L;
#pragma unroll
        for (int j = 0; j < 8; ++j) {
            ushort h = f2bf(vv[j]);
            H.u[j] = h;
            L.u[j] = f2bf(vv[j] - bf2f(h));
        }
        *(uint4*)(xh + idx) = H.q;
        *(uint4*)(xl + idx) = L.q;
    } else if (bid < 1280) {                // convert_VT (64x64 tile transpose)
        const int vb = bid - 1024;
        const int col0 = (vb & 31) * 64;
        const int d0 = (vb >> 5) * 64;
#pragma unroll
        for (int i = 0; i < 16; ++i) {
            int idx = i * 256 + tid;
            int r = idx >> 6, c = idx & 63;
            ts[r][c] = V[(size_t)(d0 + r) * NC + col0 + c];
        }
        __syncthreads();
#pragma unroll
        for (int i = 0; i < 16; ++i) {
            int idx = i * 256 + tid;
            int c2 = idx >> 6, d2 = idx & 63;
            float v = ts[d2][c2];
            ushort h = f2bf(v);
            vht[(size_t)(col0 + c2) * D + d0 + d2] = h;
            vlt[(size_t)(col0 + c2) * D + d0 + d2] = f2bf(v - bf2f(h));
        }
    } else if (bid < 1408) {                // convert_UT (one expert per block)
        const int m = bid - 1280;
        float (*t2)[129] = (float (*)[129])ts;   // 16 x 129 view
        for (int d0 = 0; d0 < D; d0 += 128) {
            __syncthreads();
#pragma unroll
            for (int i = 0; i < 8; ++i) {
                int idx = i * 256 + tid;
                int d2 = idx >> 4, b2 = idx & 15;
                t2[b2][d2] = U[(size_t)m * (D * B) + (size_t)(d0 + d2) * B + b2];
            }
            __syncthreads();
#pragma unroll
            for (int i = 0; i < 8; ++i) {
                int idx = i * 256 + tid;
                int b3 = idx >> 7, d3 = idx & 127;
                float v = t2[b3][d3];
                ushort h = f2bf(v);
                uht[(size_t)((m << 4) + b3) * D + d0 + d3] = h;
                ult[(size_t)((m << 4) + b3) * D + d0 + d3] = f2bf(v - bf2f(h));
            }
        }
    } else {                                // scales + ws-head zero
        const int bx = bid - 1408;
        if (bx >= 160) {
            ws[(bx - 160) * 256 + tid] = 0.0f;
            return;
        }
        if (bx < 32) {
            const int c = bx * 64 + (tid & 63);
            const int dg = tid >> 6;
            float s = 0.0f;
            for (int d = dg; d < D; d += 4) {
                float v = V[(size_t)d * NC + c];
                s = fmaf(v, v, s);
            }
            float (*sh)[64] = (float (*)[64])ts;
            sh[dg][tid & 63] = s;
            __syncthreads();
            if (tid < 64) {
                float t = (sh[0][tid] + sh[1][tid]) + (sh[2][tid] + sh[3][tid]);
                ws[WS_VSCALE + bx * 64 + tid] = 1.0f / sqrtf(t);
            }
        } else {
            const int m = bx - 32;
            const float* p = U + (size_t)m * (D * B);
            float s = 0.0f;
            for (int i = tid; i < D * B; i += 256) {
                float v = p[i];
                s = fmaf(v, v, s);
            }
            float* sh2 = &ts[0][0];
            sh2[tid] = s;
            __syncthreads();
            if (tid < 16) {
                float t = 0.0f;
#pragma unroll
                for (int j = 0; j < 16; ++j) t += sh2[tid + (j << 4)];
                ws[WS_USCALE + (m << 4) + tid] = tanhf(us_in[(m << 4) + tid]) / sqrtf(t);
            }
        }
    }
}

// ---------------- fused MFMA: gemm tiles (blocks 0..511) + gram tiles (512..783)
__launch_bounds__(256)
__global__ void mfma_fused(const ushort* __restrict__ xh, const ushort* __restrict__ xl,
                           const ushort* __restrict__ vht, const ushort* __restrict__ vlt,
                           const ushort* __restrict__ uht, const ushort* __restrict__ ult,
                           float* __restrict__ ws, ushort* __restrict__ rbf) {
    __shared__ ushort smem[32768];   // 2 bufs x 4 tiles x (128 rows x 32 bf16)
    const int bid = blockIdx.x;
    const int tid = threadIdx.x, lane = tid & 63, w = tid >> 6;
    const int wr = w >> 1, wc = w & 1;
    const int r15 = lane & 15, q = lane >> 4;
    const int srl = lane >> 2;
    const int skq = (lane & 3) ^ ((lane >> 3) & 3);
    const int perm8 = (q ^ ((r15 >> 1) & 3)) * 8;

    const int is_gemm = bid < 512;
    const ushort* srcs[4];
    int rbase[4];
    int gi = 0, gj = 0, which = 0;
    if (is_gemm) {
        const int tokB = (bid & 31) * 128, colB = (bid >> 5) * 128;
        srcs[0] = xh; srcs[1] = xl; srcs[2] = vht; srcs[3] = vlt;
        rbase[0] = tokB; rbase[1] = tokB; rbase[2] = colB; rbase[3] = colB;
    } else {
        int t = bid - 512;
        which = t >= 136;
        if (which) t -= 136;
        int bi = 0, rem = 16;
        while (t >= rem) { t -= rem; --rem; ++bi; }
        gi = bi; gj = bi + t;
        const ushort* ht = which ? uht : vht;
        const ushort* lt = which ? ult : vlt;
        srcs[0] = ht; srcs[1] = lt; srcs[2] = ht; srcs[3] = lt;
        rbase[0] = gi * 128; rbase[1] = gi * 128; rbase[2] = gj * 128; rbase[3] = gj * 128;
    }

    floatx4 acc[4][4];
#pragma unroll
    for (int i = 0; i < 4; ++i)
#pragma unroll
        for (int j = 0; j < 4; ++j) acc[i][j] = (floatx4){0.f, 0.f, 0.f, 0.f};

    auto stage = [&](int buf, int c) {
        const int kb = c * 32 + skq * 8;
#pragma unroll
        for (int tI = 0; tI < 4; ++tI) {
            const ushort* s = srcs[tI] + (size_t)rbase[tI] * D + kb;
#pragma unroll
            for (int sub = 0; sub < 2; ++sub) {
                const int row16 = w * 32 + sub * 16;
                GLDS16(s + (size_t)(row16 + srl) * D,
                       &smem[buf * 16384 + tI * 4096 + row16 * 32]);
            }
        }
    };

    stage(0, 0);
    for (int c = 0; c < 16; ++c) {
        __syncthreads();
        if (c < 15) stage((c + 1) & 1, c + 1);
        const ushort* bp = &smem[(c & 1) * 16384];
        short8 ah[4], al[4], bh[4], bl[4];
#pragma unroll
        for (int s = 0; s < 4; ++s) {
            const int ra = (wr * 64 + s * 16 + r15) * 32 + perm8;
            ah[s] = *(const short8*)&bp[ra];
            al[s] = *(const short8*)&bp[4096 + ra];
            const int rb = (wc * 64 + s * 16 + r15) * 32 + perm8;
            bh[s] = *(const short8*)&bp[8192 + rb];
            bl[s] = *(const short8*)&bp[12288 + rb];
        }
#pragma unroll
        for (int st = 0; st < 4; ++st)
#pragma unroll
            for (int sc = 0; sc < 4; ++sc) {
                acc[st][sc] = __builtin_amdgcn_mfma_f32_16x16x32_bf16(ah[st], bh[sc], acc[st][sc], 0, 0, 0);
                acc[st][sc] = __builtin_amdgcn_mfma_f32_16x16x32_bf16(ah[st], bl[sc], acc[st][sc], 0, 0, 0);
                acc[st][sc] = __builtin_amdgcn_mfma_f32_16x16x32_bf16(al[st], bh[sc], acc[st][sc], 0, 0, 0);
            }
    }

    if (is_gemm) {
        const int tok0 = (bid & 31) * 128 + wr * 64, col0 = (bid >> 5) * 128 + wc * 64;
#pragma unroll
        for (int sc = 0; sc < 4; ++sc) {
            const int colg = col0 + sc * 16 + r15;
            const float vs = ws[WS_VSCALE + colg];
            const int ex = colg >> 4;
#pragma unroll
            for (int st = 0; st < 4; ++st) {
                const int rowb = tok0 + st * 16 + q * 4;
                float r0 = acc[st][sc][0] * vs;
                float r1 = acc[st][sc][1] * vs;
                float r2 = acc[st][sc][2] * vs;
                float r3 = acc[st][sc][3] * vs;
                rbf[(size_t)(rowb + 0) * NC + colg] = f2bf(r0);
                rbf[(size_t)(rowb + 1) * NC + colg] = f2bf(r1);
                rbf[(size_t)(rowb + 2) * NC + colg] = f2bf(r2);
                rbf[(size_t)(rowb + 3) * NC + colg] = f2bf(r3);
                float e0 = r0 * r0, e1 = r1 * r1, e2 = r2 * r2, e3 = r3 * r3;
#pragma unroll
                for (int mk = 1; mk < 16; mk <<= 1) {
                    e0 += __shfl_xor(e0, mk);
                    e1 += __shfl_xor(e1, mk);
                    e2 += __shfl_xor(e2, mk);
                    e3 += __shfl_xor(e3, mk);
                }
                if (r15 == 0) {
                    float* ep = ws + WS_E_F + (size_t)rowb * M + ex;
                    ep[0] = e0; ep[M] = e1; ep[2 * M] = e2; ep[3 * M] = e3;
                }
            }
        }
    } else {
        const float* scl = ws + (which ? WS_USCALE : WS_VSCALE);
        float* sum_out = ws + (which ? WS_USUM : WS_VSUM);
        float local = 0.0f;
#pragma unroll
        for (int sc = 0; sc < 4; ++sc) {
            const int colg = gj * 128 + wc * 64 + sc * 16 + r15;
            const float scj = scl[colg];
#pragma unroll
            for (int st = 0; st < 4; ++st) {
#pragma unroll
                for (int reg = 0; reg < 4; ++reg) {
                    const int rowg = gi * 128 + wr * 64 + st * 16 + q * 4 + reg;
                    float g = acc[st][sc][reg] * scl[rowg] * scj;
                    if (rowg == colg) g -= 1.0f;
                    local += fabsf(g);
                }
            }
        }
        if (gi < gj) local *= 2.0f;
#pragma unroll
        for (int mk = 1; mk < 64; mk <<= 1) local += __shfl_xor(local, mk);
        __shared__ float red[4];
        if (lane == 0) red[w] = local;
        __syncthreads();
        if (tid == 0) atomicAdd(sum_out, (red[0] + red[1]) + (red[2] + red[3]));
    }
}

// Wave-per-token top-4 with robustness gate (unchanged from round 11).
__launch_bounds__(256)
__global__ void topk_kernel(float* __restrict__ ws) {
    const int tid = threadIdx.x, lane = tid & 63, w = tid >> 6;
    const int t = blockIdx.x * 4 + w;
    int* icnt = (int*)ws + WS_CNT_I;
    int* ilist = (int*)(ws + WS_LIST_F);

    const float2 ev = *(const float2*)(ws + WS_E_F + (size_t)t * M + lane * 2);
    const uint i0 = (uint)(lane * 2), i1 = i0 + 1;
    u64 k0 = ((u64)__float_as_uint(ev.x) << 32) | (uint)(~i0);
    u64 k1 = ((u64)__float_as_uint(ev.y) << 32) | (uint)(~i1);
    u64 s0 = k0 > k1 ? k0 : k1;
    u64 s1 = k0 > k1 ? k1 : k0;
    u64 s2 = 0, s3 = 0;

#pragma unroll
    for (int mk = 1; mk < 64; mk <<= 1) {
        u64 o0 = __shfl_xor(s0, mk);
        u64 o1 = __shfl_xor(s1, mk);
        u64 o2 = __shfl_xor(s2, mk);
        u64 o3 = __shfl_xor(s3, mk);
        u64 c0 = s0 > o3 ? s0 : o3;
        u64 c1 = s1 > o2 ? s1 : o2;
        u64 c2 = s2 > o1 ? s2 : o1;
        u64 c3 = s3 > o0 ? s3 : o0;
        u64 d0 = c0 > c2 ? c0 : c2, d2 = c0 > c2 ? c2 : c0;
        u64 d1 = c1 > c3 ? c1 : c3, d3 = c1 > c3 ? c3 : c1;
        s0 = d0 > d1 ? d0 : d1; s1 = d0 > d1 ? d1 : d0;
        s2 = d2 > d3 ? d2 : d3; s3 = d2 > d3 ? d3 : d2;
    }

    u64 m0 = (k0 == s0 || k0 == s1 || k0 == s2 || k0 == s3) ? 0 : k0;
    u64 m1 = (k1 == s0 || k1 == s1 || k1 == s2 || k1 == s3) ? 0 : k1;
    u64 mx = m0 > m1 ? m0 : m1;
#pragma unroll
    for (int mk = 1; mk < 64; mk <<= 1) {
        u64 om = __shfl_xor(mx, mk);
        if (om > mx) mx = om;
    }

    const float e4 = __uint_as_float((uint)(s3 >> 32));
    const float e5 = __uint_as_float((uint)(mx >> 32));
    const bool robust = (e4 - e5) > 1e-3f * e4;

    if (robust) {
        if (lane < 4) {
            u64 key = (lane == 0) ? s0 : (lane == 1) ? s1 : (lane == 2) ? s2 : s3;
            const int e = (int)(~(uint)key);
            const float val = __uint_as_float((uint)(key >> 32));
            atomicAdd(&ws[WS_EACC + e], val);
            atomicAdd(&ws[WS_CACC + e], 1.0f);
            int pos = atomicAdd(&icnt[e], 1);
            ilist[(e << 12) + pos] = (t << 2) | lane;
        }
    } else {
        if (lane == 0) {
            int* rc = (int*)ws + WS_RCNT_I;
            int p = atomicAdd(rc, 1);
            ((int*)(ws + WS_RLIST_F))[p] = t;
        }
    }
}

// Candidate-restricted fp64 recheck: per deferred token, recompute only the
// experts within 2e-3 of the 4th-best fp32 energy (true top-4 provably inside;
// typically 5-7, cap 16). One (candidate, b)-column per thread: lanes of one
// expert read a single contiguous 64B line per d-step. fp32 vscale^2 for the
// norm (1e-7 rel — below np's own fp32 noise).
__launch_bounds__(256)
__global__ void recheck_kernel(const float* __restrict__ x,
                               const float* __restrict__ V,
                               float* __restrict__ ws) {
    const int rcnt = ((const int*)ws)[WS_RCNT_I];
    __shared__ float Esh[128];
    __shared__ float xs[512];
    __shared__ int cand[16];
    __shared__ int ncand_sh;
    __shared__ double Ecand[16];
    const int tid = threadIdx.x;

    for (int ri = blockIdx.x; ri < rcnt; ri += gridDim.x) {
        const int t = ((const int*)(ws + WS_RLIST_F))[ri];
        if (tid < 128) {
            Esh[tid] = ws[WS_E_F + (size_t)t * M + tid];
            *(float4*)&xs[tid * 4] = *(const float4*)(x + (size_t)t * D + tid * 4);
        }
        __syncthreads();

        if (tid == 0) {
            // 4th-largest value (values only)
            float b0 = -1e30f, b1 = -1e30f, b2 = -1e30f, b3 = -1e30f;
            for (int m = 0; m < M; ++m) {
                float v = Esh[m];
                if (v > b3) {
                    if (v > b0) { b3 = b2; b2 = b1; b1 = b0; b0 = v; }
                    else if (v > b1) { b3 = b2; b2 = b1; b1 = v; }
                    else if (v > b2) { b3 = b2; b2 = v; }
                    else { b3 = v; }
                }
            }
            const float thresh = b3 - 2e-3f * b3;
            int nc = 0;
            for (int m = 0; m < M && nc < 16; ++m)
                if (Esh[m] >= thresh) cand[nc++] = m;
            ncand_sh = nc;
        }
        __syncthreads();
        const int ncand = ncand_sh;

        const int ci = tid >> 4, b = tid & 15;
        int c = 0;
        double d0a = 0.0, d1a = 0.0;
        if (ci < ncand) {
            c = (cand[ci] << 4) + b;
            const float* vp = V + c;
            for (int d = 0; d < D; d += 2) {
                d0a += (double)xs[d] * (double)vp[(size_t)d * NC];
                d1a += (double)xs[d + 1] * (double)vp[(size_t)(d + 1) * NC];
            }
        }
        double e = d0a + d1a;
        double sc = (ci < ncand) ? (double)ws[WS_VSCALE + c] : 0.0;
        e = (e * e) * (sc * sc);
#pragma unroll
        for (int mk = 1; mk < 16; mk <<= 1) e += __shfl_xor(e, mk);
        if (ci < ncand && b == 0 && ci < 16) Ecand[ci] = e;
        __syncthreads();

        if (tid == 0) {
            double bv0 = -1.0, bv1 = -1.0, bv2 = -1.0, bv3 = -1.0;
            int bi0 = 0, bi1 = 0, bi2 = 0, bi3 = 0;
            for (int j = 0; j < ncand; ++j) {
                double v = Ecand[j];
                const int m = cand[j];
                if (v > bv3) {
                    if (v > bv0) {
                        bv3 = bv2; bi3 = bi2; bv2 = bv1; bi2 = bi1; bv1 = bv0; bi1 = bi0;
                        bv0 = v; bi0 = m;
                    } else if (v > bv1) {
                        bv3 = bv2; bi3 = bi2; bv2 = bv1; bi2 = bi1;
                        bv1 = v; bi1 = m;
                    } else if (v > bv2) {
                        bv3 = bv2; bi3 = bi2;
                        bv2 = v; bi2 = m;
                    } else {
                        bv3 = v; bi3 = m;
                    }
                }
            }
            int sel[4] = {bi0, bi1, bi2, bi3};
            int* icnt = (int*)ws + WS_CNT_I;
            int* ilist = (int*)(ws + WS_LIST_F);
#pragma unroll
            for (int k = 0; k < 4; ++k) {
                const int e2 = sel[k];
                atomicAdd(&ws[WS_EACC + e2], Esh[e2]);
                atomicAdd(&ws[WS_CACC + e2], 1.0f);
                int pos = atomicAdd(&icnt[e2], 1);
                ilist[(e2 << 12) + pos] = (t << 2) | k;
            }
        }
        __syncthreads();
    }
}

// Expert-major contributions: contrib[t][k][d] (bf16 pairs packed in uint).
__launch_bounds__(256)
__global__ void expert_contrib_kernel(const float* __restrict__ U,
                                      const ushort* __restrict__ rbf,
                                      const float* __restrict__ ws,
                                      uint* __restrict__ contrib) {
    const int e = blockIdx.x;
    const int tid = threadIdx.x;
    const int cnt = ((const int*)ws)[WS_CNT_I + e];
    if ((int)blockIdx.y >= cnt) return;

    float usc[16];
#pragma unroll
    for (int b = 0; b < 16; ++b) usc[b] = ws[WS_USCALE + (e << 4) + b];

    const float* Up = U + (size_t)e * (D * B);
    float u0[16], u1[16];
#pragma unroll
    for (int qd = 0; qd < 4; ++qd) {
        float4 a = *(const float4*)(Up + (size_t)(2 * tid) * B + qd * 4);
        float4 b4 = *(const float4*)(Up + (size_t)(2 * tid + 1) * B + qd * 4);
        u0[qd * 4 + 0] = a.x * usc[qd * 4 + 0];
        u0[qd * 4 + 1] = a.y * usc[qd * 4 + 1];
        u0[qd * 4 + 2] = a.z * usc[qd * 4 + 2];
        u0[qd * 4 + 3] = a.w * usc[qd * 4 + 3];
        u1[qd * 4 + 0] = b4.x * usc[qd * 4 + 0];
        u1[qd * 4 + 1] = b4.y * usc[qd * 4 + 1];
        u1[qd * 4 + 2] = b4.z * usc[qd * 4 + 2];
        u1[qd * 4 + 3] = b4.w * usc[qd * 4 + 3];
    }

    const int* ilist = (const int*)(ws + WS_LIST_F) + (e << 12);
    int i = blockIdx.y;
    int pk = (i < cnt) ? ilist[i] : 0;
    while (i < cnt) {
        const int t = pk >> 2, k = pk & 3;
        const ushort* rp = rbf + (size_t)t * NC + (e << 4);
        union { ushort u[16]; uint4 q[2]; } R;
        R.q[0] = *(const uint4*)(rp);
        R.q[1] = *(const uint4*)(rp + 8);
        const int inext = i + 4;
        if (inext < cnt) pk = ilist[inext];
        float acc0 = 0.0f, acc1 = 0.0f;
#pragma unroll
        for (int b = 0; b < 16; ++b) {
            const float wv = bf2f(R.u[b]);
            acc0 = fmaf(u0[b], wv, acc0);
            acc1 = fmaf(u1[b], wv, acc1);
        }
        contrib[(size_t)((t << 2) + k) * 256 + tid] =
            (uint)f2bf(acc0) | ((uint)f2bf(acc1) << 16);
        i = inext;
    }
}

// blocks 0..1023: out = x + sum_k contrib  ; block 1024: finalize scalars
__launch_bounds__(256)
__global__ void combine_kernel(const float* __restrict__ x,
                               const uint* __restrict__ contrib,
                               const float* __restrict__ ws,
                               float* __restrict__ out) {
    if (blockIdx.x == 1024) {               // finalize
        const int m = threadIdx.x;
        if (m >= 128) return;
        float e = ws[WS_EACC + m] * (1.0f / (float)NTOK);
        float c = ws[WS_CACC + m] * (1.0f / (float)NTOK);
        float s = e;
#pragma unroll
        for (int off = 32; off > 0; off >>= 1) s += __shfl_down(s, off);
        __shared__ float sh[2];
        if ((m & 63) == 0) sh[m >> 6] = s;
        __syncthreads();
        float total = sh[0] + sh[1];
        float total_energy = fmaxf(total, 1e-12f);
        out[OUT_EPE + m] = e;
        out[OUT_RE + m] = e / total_energy;
        out[OUT_SR + m] = c;
        if (m == 0) {
            out[OUT_TE] = total_energy;
            float inv_n2 = 1.0f / ((float)NC * (float)NC);
            float sqrtD = sqrtf((float)D);
            float vpen = ws[WS_VSUM] * inv_n2 * sqrtD;
            float upen = ws[WS_USUM] * inv_n2 * sqrtD;
            out[OUT_VPEN] = vpen;
            out[OUT_UPEN] = upen;
            out[OUT_AUX] = 0.01f * vpen - total_energy;
        }
        return;
    }

    const int gid = blockIdx.x * 256 + threadIdx.x;
    const int t = gid >> 6;
    const int dq = (gid & 63) << 3;
    const uint4* cp = (const uint4*)contrib;

    float s[8];
    float4 x0 = *(const float4*)(x + (size_t)t * D + dq);
    float4 x1 = *(const float4*)(x + (size_t)t * D + dq + 4);
    s[0] = x0.x; s[1] = x0.y; s[2] = x0.z; s[3] = x0.w;
    s[4] = x1.x; s[5] = x1.y; s[6] = x1.z; s[7] = x1.w;
#pragma unroll
    for (int k = 0; k < KSEL; ++k) {
        uint4 cvec = cp[(size_t)((t << 2) + k) * 64 + (dq >> 3)];
        uint cc[4] = {cvec.x, cvec.y, cvec.z, cvec.w};
#pragma unroll
        for (int j = 0; j < 4; ++j) {
            s[2 * j]     += bf2f((ushort)(cc[j] & 0xffffu));
            s[2 * j + 1] += bf2f((ushort)(cc[j] >> 16));
        }
    }
    float* op = out + (size_t)t * D + dq;
    *(float4*)(op)     = make_float4(s[0], s[1], s[2], s[3]);
    *(float4*)(op + 4) = make_float4(s[4], s[5], s[6], s[7]);
}

extern "C" void kernel_launch(void* const* d_in, const int* in_sizes, int n_in,
                              void* d_out, int out_size, void* d_ws, size_t ws_size,
                              hipStream_t stream) {
    const float* x  = (const float*)d_in[0];
    const float* V  = (const float*)d_in[1];
    const float* U  = (const float*)d_in[2];
    const float* us = (const float*)d_in[3];
    float* out = (float*)d_out;
    float* ws  = (float*)d_ws;

    ushort* xh  = (ushort*)(ws + WS_XH_F);
    ushort* xl  = (ushort*)(ws + WS_XL_F);
    ushort* vht = (ushort*)(ws + WS_VHT_F);
    ushort* vlt = (ushort*)(ws + WS_VLT_F);
    ushort* uht = (ushort*)(ws + WS_UHT_F);
    ushort* ult = (ushort*)(ws + WS_ULT_F);
    ushort* rbf = (ushort*)(ws + WS_RBF_F);
    uint* contrib = (uint*)(ws + WS_XH_F);   // reuses xh..ult after mfma_fused

    prep_kernel<<<1570, 256, 0, stream>>>(x, V, U, us, xh, xl, vht, vlt, uht, ult, ws);
    mfma_fused<<<784, 256, 0, stream>>>(xh, xl, vht, vlt, uht, ult, ws, rbf);
    topk_kernel<<<NTOK / 4, 256, 0, stream>>>(ws);
    recheck_kernel<<<128, 256, 0, stream>>>(x, V, ws);
    expert_contrib_kernel<<<dim3(128, 4), 256, 0, stream>>>(U, rbf, ws, contrib);
    combine_kernel<<<1025, 256, 0, stream>>>(x, contrib, ws, out);
}

// Round 13
// 252.302 us; speedup vs baseline: 1.9112x; 1.0634x over previous
//
#include <hip/hip_runtime.h>
#include <math.h>

#define D 512
#define M 128
#define B 16
#define KSEL 4
#define NC 2048           // M*B
#define NTOK 4096         // 2*2048

typedef unsigned short ushort;
typedef unsigned int uint;
typedef unsigned long long u64;
typedef __attribute__((ext_vector_type(8))) short short8;   // 8 bf16 (4 VGPRs)
typedef __attribute__((ext_vector_type(4))) float floatx4;  // 4 fp32 acc

// ws layout (float indices)
#define WS_EACC   0       // [128]
#define WS_CACC   128     // [128]
#define WS_VSUM   256     // [1]
#define WS_USUM   257     // [1]
#define WS_CNT_I  258     // int counters [128] (inside zeroed first 512 floats)
#define WS_RCNT_I 386     // int recheck counter (inside zeroed head)
#define WS_VSCALE 512     // [2048] 1/||V col||
#define WS_USCALE 2560    // [2048] tanh(us)/||U col||
#define WS_E_F    4608    // [NTOK*M] fp32 energies, 2 MB
#define WS_RBF_F  528896  // R bf16 [NTOK][NC] (16 MB)
#define WS_XH_F   2626048 // xh bf16 [NTOK][D]; REUSED as contrib after mfma_fused
#define WS_XL_F   3674624 // xl bf16
#define WS_VHT_F  4723200 // VhT bf16 [NC][D]
#define WS_VLT_F  5247488
#define WS_UHT_F  5771776 // UhT bf16 [NC][D] (col = m*16+b)
#define WS_ULT_F  6296064
#define WS_LIST_F 6820352 // int [128][4096] per-expert token lists, packed (t<<2)|k
#define WS_RLIST_F 7344640 // int [4096] recheck token list
                           // end: 7348736 floats = 29.4 MB (ws >= 35.7 MB proven)

// out layout (floats)
#define OUT_TE   2097152
#define OUT_EPE  2097153
#define OUT_RE   2097281
#define OUT_SR   2097409
#define OUT_VPEN 2097537
#define OUT_UPEN 2097538
#define OUT_AUX  2097539

#define GLDS16(g, l) __builtin_amdgcn_global_load_lds(                        \
    (const __attribute__((address_space(1))) unsigned int*)(g),               \
    (__attribute__((address_space(3))) unsigned int*)(l), 16, 0, 0)

__device__ __forceinline__ ushort f2bf(float f) {   // RNE
    union { float f; uint u; } a; a.f = f;
    uint u = a.u;
    u += 0x7fffu + ((u >> 16) & 1u);
    return (ushort)(u >> 16);
}
__device__ __forceinline__ float bf2f(ushort h) {
    union { uint u; float f; } a; a.u = ((uint)h) << 16;
    return a.f;
}

// ---------------- fused prep: converts + scales + ws-zero (1570 blocks) ----
__launch_bounds__(256)
__global__ void prep_kernel(const float* __restrict__ x, const float* __restrict__ V,
                            const float* __restrict__ U, const float* __restrict__ us_in,
                            ushort* __restrict__ xh, ushort* __restrict__ xl,
                            ushort* __restrict__ vht, ushort* __restrict__ vlt,
                            ushort* __restrict__ uht, ushort* __restrict__ ult,
                            float* __restrict__ ws) {
    __shared__ float ts[64][65];
    const int bid = blockIdx.x;
    const int tid = threadIdx.x;

    if (bid < 1024) {                       // convert_x
        const int idx = (bid * 256 + tid) * 8;
        float4 v0 = *(const float4*)(x + idx);
        float4 v1 = *(const float4*)(x + idx + 4);
        float vv[8] = {v0.x, v0.y, v0.z, v0.w, v1.x, v1.y, v1.z, v1.w};
        union { ushort u[8]; uint4 q; } H, L;
#pragma unroll
        for (int j = 0; j < 8; ++j) {
            ushort h = f2bf(vv[j]);
            H.u[j] = h;
            L.u[j] = f2bf(vv[j] - bf2f(h));
        }
        *(uint4*)(xh + idx) = H.q;
        *(uint4*)(xl + idx) = L.q;
    } else if (bid < 1280) {                // convert_VT (64x64 tile transpose)
        const int vb = bid - 1024;
        const int col0 = (vb & 31) * 64;
        const int d0 = (vb >> 5) * 64;
#pragma unroll
        for (int i = 0; i < 16; ++i) {
            int idx = i * 256 + tid;
            int r = idx >> 6, c = idx & 63;
            ts[r][c] = V[(size_t)(d0 + r) * NC + col0 + c];
        }
        __syncthreads();
#pragma unroll
        for (int i = 0; i < 16; ++i) {
            int idx = i * 256 + tid;
            int c2 = idx >> 6, d2 = idx & 63;
            float v = ts[d2][c2];
            ushort h = f2bf(v);
            vht[(size_t)(col0 + c2) * D + d0 + d2] = h;
            vlt[(size_t)(col0 + c2) * D + d0 + d2] = f2bf(v - bf2f(h));
        }
    } else if (bid < 1408) {                // convert_UT (one expert per block)
        const int m = bid - 1280;
        float (*t2)[129] = (float (*)[129])ts;   // 16 x 129 view
        for (int d0 = 0; d0 < D; d0 += 128) {
            __syncthreads();
#pragma unroll
            for (int i = 0; i < 8; ++i) {
                int idx = i * 256 + tid;
                int d2 = idx >> 4, b2 = idx & 15;
                t2[b2][d2] = U[(size_t)m * (D * B) + (size_t)(d0 + d2) * B + b2];
            }
            __syncthreads();
#pragma unroll
            for (int i = 0; i < 8; ++i) {
                int idx = i * 256 + tid;
                int b3 = idx >> 7, d3 = idx & 127;
                float v = t2[b3][d3];
                ushort h = f2bf(v);
                uht[(size_t)((m << 4) + b3) * D + d0 + d3] = h;
                ult[(size_t)((m << 4) + b3) * D + d0 + d3] = f2bf(v - bf2f(h));
            }
        }
    } else {                                // scales + ws-head zero
        const int bx = bid - 1408;
        if (bx >= 160) {
            ws[(bx - 160) * 256 + tid] = 0.0f;
            return;
        }
        if (bx < 32) {
            const int c = bx * 64 + (tid & 63);
            const int dg = tid >> 6;
            float s = 0.0f;
            for (int d = dg; d < D; d += 4) {
                float v = V[(size_t)d * NC + c];
                s = fmaf(v, v, s);
            }
            float (*sh)[64] = (float (*)[64])ts;
            sh[dg][tid & 63] = s;
            __syncthreads();
            if (tid < 64) {
                float t = (sh[0][tid] + sh[1][tid]) + (sh[2][tid] + sh[3][tid]);
                ws[WS_VSCALE + bx * 64 + tid] = 1.0f / sqrtf(t);
            }
        } else {
            const int m = bx - 32;
            const float* p = U + (size_t)m * (D * B);
            float s = 0.0f;
            for (int i = tid; i < D * B; i += 256) {
                float v = p[i];
                s = fmaf(v, v, s);
            }
            float* sh2 = &ts[0][0];
            sh2[tid] = s;
            __syncthreads();
            if (tid < 16) {
                float t = 0.0f;
#pragma unroll
                for (int j = 0; j < 16; ++j) t += sh2[tid + (j << 4)];
                ws[WS_USCALE + (m << 4) + tid] = tanhf(us_in[(m << 4) + tid]) / sqrtf(t);
            }
        }
    }
}

// ---------------- fused MFMA: gemm tiles (blocks 0..511) + gram tiles (512..783)
__launch_bounds__(256)
__global__ void mfma_fused(const ushort* __restrict__ xh, const ushort* __restrict__ xl,
                           const ushort* __restrict__ vht, const ushort* __restrict__ vlt,
                           const ushort* __restrict__ uht, const ushort* __restrict__ ult,
                           float* __restrict__ ws, ushort* __restrict__ rbf) {
    __shared__ ushort smem[32768];   // 2 bufs x 4 tiles x (128 rows x 32 bf16)
    const int bid = blockIdx.x;
    const int tid = threadIdx.x, lane = tid & 63, w = tid >> 6;
    const int wr = w >> 1, wc = w & 1;
    const int r15 = lane & 15, q = lane >> 4;
    const int srl = lane >> 2;
    const int skq = (lane & 3) ^ ((lane >> 3) & 3);
    const int perm8 = (q ^ ((r15 >> 1) & 3)) * 8;

    const int is_gemm = bid < 512;
    const ushort* srcs[4];
    int rbase[4];
    int gi = 0, gj = 0, which = 0;
    if (is_gemm) {
        const int tokB = (bid & 31) * 128, colB = (bid >> 5) * 128;
        srcs[0] = xh; srcs[1] = xl; srcs[2] = vht; srcs[3] = vlt;
        rbase[0] = tokB; rbase[1] = tokB; rbase[2] = colB; rbase[3] = colB;
    } else {
        int t = bid - 512;
        which = t >= 136;
        if (which) t -= 136;
        int bi = 0, rem = 16;
        while (t >= rem) { t -= rem; --rem; ++bi; }
        gi = bi; gj = bi + t;
        const ushort* ht = which ? uht : vht;
        const ushort* lt = which ? ult : vlt;
        srcs[0] = ht; srcs[1] = lt; srcs[2] = ht; srcs[3] = lt;
        rbase[0] = gi * 128; rbase[1] = gi * 128; rbase[2] = gj * 128; rbase[3] = gj * 128;
    }

    floatx4 acc[4][4];
#pragma unroll
    for (int i = 0; i < 4; ++i)
#pragma unroll
        for (int j = 0; j < 4; ++j) acc[i][j] = (floatx4){0.f, 0.f, 0.f, 0.f};

    auto stage = [&](int buf, int c) {
        const int kb = c * 32 + skq * 8;
#pragma unroll
        for (int tI = 0; tI < 4; ++tI) {
            const ushort* s = srcs[tI] + (size_t)rbase[tI] * D + kb;
#pragma unroll
            for (int sub = 0; sub < 2; ++sub) {
                const int row16 = w * 32 + sub * 16;
                GLDS16(s + (size_t)(row16 + srl) * D,
                       &smem[buf * 16384 + tI * 4096 + row16 * 32]);
            }
        }
    };

    stage(0, 0);
    for (int c = 0; c < 16; ++c) {
        __syncthreads();
        if (c < 15) stage((c + 1) & 1, c + 1);
        const ushort* bp = &smem[(c & 1) * 16384];
        short8 ah[4], al[4], bh[4], bl[4];
#pragma unroll
        for (int s = 0; s < 4; ++s) {
            const int ra = (wr * 64 + s * 16 + r15) * 32 + perm8;
            ah[s] = *(const short8*)&bp[ra];
            al[s] = *(const short8*)&bp[4096 + ra];
            const int rb = (wc * 64 + s * 16 + r15) * 32 + perm8;
            bh[s] = *(const short8*)&bp[8192 + rb];
            bl[s] = *(const short8*)&bp[12288 + rb];
        }
#pragma unroll
        for (int st = 0; st < 4; ++st)
#pragma unroll
            for (int sc = 0; sc < 4; ++sc) {
                acc[st][sc] = __builtin_amdgcn_mfma_f32_16x16x32_bf16(ah[st], bh[sc], acc[st][sc], 0, 0, 0);
                acc[st][sc] = __builtin_amdgcn_mfma_f32_16x16x32_bf16(ah[st], bl[sc], acc[st][sc], 0, 0, 0);
                acc[st][sc] = __builtin_amdgcn_mfma_f32_16x16x32_bf16(al[st], bh[sc], acc[st][sc], 0, 0, 0);
            }
    }

    if (is_gemm) {
        const int tok0 = (bid & 31) * 128 + wr * 64, col0 = (bid >> 5) * 128 + wc * 64;
#pragma unroll
        for (int sc = 0; sc < 4; ++sc) {
            const int colg = col0 + sc * 16 + r15;
            const float vs = ws[WS_VSCALE + colg];
            const int ex = colg >> 4;
#pragma unroll
            for (int st = 0; st < 4; ++st) {
                const int rowb = tok0 + st * 16 + q * 4;
                float r0 = acc[st][sc][0] * vs;
                float r1 = acc[st][sc][1] * vs;
                float r2 = acc[st][sc][2] * vs;
                float r3 = acc[st][sc][3] * vs;
                rbf[(size_t)(rowb + 0) * NC + colg] = f2bf(r0);
                rbf[(size_t)(rowb + 1) * NC + colg] = f2bf(r1);
                rbf[(size_t)(rowb + 2) * NC + colg] = f2bf(r2);
                rbf[(size_t)(rowb + 3) * NC + colg] = f2bf(r3);
                float e0 = r0 * r0, e1 = r1 * r1, e2 = r2 * r2, e3 = r3 * r3;
#pragma unroll
                for (int mk = 1; mk < 16; mk <<= 1) {
                    e0 += __shfl_xor(e0, mk);
                    e1 += __shfl_xor(e1, mk);
                    e2 += __shfl_xor(e2, mk);
                    e3 += __shfl_xor(e3, mk);
                }
                if (r15 == 0) {
                    float* ep = ws + WS_E_F + (size_t)rowb * M + ex;
                    ep[0] = e0; ep[M] = e1; ep[2 * M] = e2; ep[3 * M] = e3;
                }
            }
        }
    } else {
        const float* scl = ws + (which ? WS_USCALE : WS_VSCALE);
        float* sum_out = ws + (which ? WS_USUM : WS_VSUM);
        float local = 0.0f;
#pragma unroll
        for (int sc = 0; sc < 4; ++sc) {
            const int colg = gj * 128 + wc * 64 + sc * 16 + r15;
            const float scj = scl[colg];
#pragma unroll
            for (int st = 0; st < 4; ++st) {
#pragma unroll
                for (int reg = 0; reg < 4; ++reg) {
                    const int rowg = gi * 128 + wr * 64 + st * 16 + q * 4 + reg;
                    float g = acc[st][sc][reg] * scl[rowg] * scj;
                    if (rowg == colg) g -= 1.0f;
                    local += fabsf(g);
                }
            }
        }
        if (gi < gj) local *= 2.0f;
#pragma unroll
        for (int mk = 1; mk < 64; mk <<= 1) local += __shfl_xor(local, mk);
        __shared__ float red[4];
        if (lane == 0) red[w] = local;
        __syncthreads();
        if (tid == 0) atomicAdd(sum_out, (red[0] + red[1]) + (red[2] + red[3]));
    }
}

// Wave-per-token top-4 with robustness gate (unchanged from round 11).
__launch_bounds__(256)
__global__ void topk_kernel(float* __restrict__ ws) {
    const int tid = threadIdx.x, lane = tid & 63, w = tid >> 6;
    const int t = blockIdx.x * 4 + w;
    int* icnt = (int*)ws + WS_CNT_I;
    int* ilist = (int*)(ws + WS_LIST_F);

    const float2 ev = *(const float2*)(ws + WS_E_F + (size_t)t * M + lane * 2);
    const uint i0 = (uint)(lane * 2), i1 = i0 + 1;
    u64 k0 = ((u64)__float_as_uint(ev.x) << 32) | (uint)(~i0);
    u64 k1 = ((u64)__float_as_uint(ev.y) << 32) | (uint)(~i1);
    u64 s0 = k0 > k1 ? k0 : k1;
    u64 s1 = k0 > k1 ? k1 : k0;
    u64 s2 = 0, s3 = 0;

#pragma unroll
    for (int mk = 1; mk < 64; mk <<= 1) {
        u64 o0 = __shfl_xor(s0, mk);
        u64 o1 = __shfl_xor(s1, mk);
        u64 o2 = __shfl_xor(s2, mk);
        u64 o3 = __shfl_xor(s3, mk);
        u64 c0 = s0 > o3 ? s0 : o3;
        u64 c1 = s1 > o2 ? s1 : o2;
        u64 c2 = s2 > o1 ? s2 : o1;
        u64 c3 = s3 > o0 ? s3 : o0;
        u64 d0 = c0 > c2 ? c0 : c2, d2 = c0 > c2 ? c2 : c0;
        u64 d1 = c1 > c3 ? c1 : c3, d3 = c1 > c3 ? c3 : c1;
        s0 = d0 > d1 ? d0 : d1; s1 = d0 > d1 ? d1 : d0;
        s2 = d2 > d3 ? d2 : d3; s3 = d2 > d3 ? d3 : d2;
    }

    u64 m0 = (k0 == s0 || k0 == s1 || k0 == s2 || k0 == s3) ? 0 : k0;
    u64 m1 = (k1 == s0 || k1 == s1 || k1 == s2 || k1 == s3) ? 0 : k1;
    u64 mx = m0 > m1 ? m0 : m1;
#pragma unroll
    for (int mk = 1; mk < 64; mk <<= 1) {
        u64 om = __shfl_xor(mx, mk);
        if (om > mx) mx = om;
    }

    const float e4 = __uint_as_float((uint)(s3 >> 32));
    const float e5 = __uint_as_float((uint)(mx >> 32));
    const bool robust = (e4 - e5) > 1e-3f * e4;

    if (robust) {
        if (lane < 4) {
            u64 key = (lane == 0) ? s0 : (lane == 1) ? s1 : (lane == 2) ? s2 : s3;
            const int e = (int)(~(uint)key);
            const float val = __uint_as_float((uint)(key >> 32));
            atomicAdd(&ws[WS_EACC + e], val);
            atomicAdd(&ws[WS_CACC + e], 1.0f);
            int pos = atomicAdd(&icnt[e], 1);
            ilist[(e << 12) + pos] = (t << 2) | lane;
        }
    } else {
        if (lane == 0) {
            int* rc = (int*)ws + WS_RCNT_I;
            int p = atomicAdd(rc, 1);
            ((int*)(ws + WS_RLIST_F))[p] = t;
        }
    }
}

// Candidate-restricted fp64 recheck. Round-13 change: 8 independent fp64
// accumulators (8 outstanding loads — kills the 2-deep dependent load chain)
// and grid 512 so ~1 deferred token per block.
__launch_bounds__(256)
__global__ void recheck_kernel(const float* __restrict__ x,
                               const float* __restrict__ V,
                               float* __restrict__ ws) {
    const int rcnt = ((const int*)ws)[WS_RCNT_I];
    __shared__ float Esh[128];
    __shared__ float xs[512];
    __shared__ int cand[16];
    __shared__ int ncand_sh;
    __shared__ double Ecand[16];
    const int tid = threadIdx.x;

    for (int ri = blockIdx.x; ri < rcnt; ri += gridDim.x) {
        const int t = ((const int*)(ws + WS_RLIST_F))[ri];
        if (tid < 128) {
            Esh[tid] = ws[WS_E_F + (size_t)t * M + tid];
            *(float4*)&xs[tid * 4] = *(const float4*)(x + (size_t)t * D + tid * 4);
        }
        __syncthreads();

        if (tid == 0) {
            float b0 = -1e30f, b1 = -1e30f, b2 = -1e30f, b3 = -1e30f;
            for (int m = 0; m < M; ++m) {
                float v = Esh[m];
                if (v > b3) {
                    if (v > b0) { b3 = b2; b2 = b1; b1 = b0; b0 = v; }
                    else if (v > b1) { b3 = b2; b2 = b1; b1 = v; }
                    else if (v > b2) { b3 = b2; b2 = v; }
                    else { b3 = v; }
                }
            }
            const float thresh = b3 - 2e-3f * b3;
            int nc = 0;
            for (int m = 0; m < M && nc < 16; ++m)
                if (Esh[m] >= thresh) cand[nc++] = m;
            ncand_sh = nc;
        }
        __syncthreads();
        const int ncand = ncand_sh;

        const int ci = tid >> 4, b = tid & 15;
        int c = 0;
        double pa[8] = {0, 0, 0, 0, 0, 0, 0, 0};
        if (ci < ncand) {
            c = (cand[ci] << 4) + b;
            const float* vp = V + c;
            for (int d = 0; d < D; d += 8) {
#pragma unroll
                for (int j = 0; j < 8; ++j)
                    pa[j] += (double)xs[d + j] * (double)vp[(size_t)(d + j) * NC];
            }
        }
        double e = ((pa[0] + pa[1]) + (pa[2] + pa[3])) +
                   ((pa[4] + pa[5]) + (pa[6] + pa[7]));
        double sc = (ci < ncand) ? (double)ws[WS_VSCALE + c] : 0.0;
        e = (e * e) * (sc * sc);
#pragma unroll
        for (int mk = 1; mk < 16; mk <<= 1) e += __shfl_xor(e, mk);
        if (ci < ncand && b == 0 && ci < 16) Ecand[ci] = e;
        __syncthreads();

        if (tid == 0) {
            double bv0 = -1.0, bv1 = -1.0, bv2 = -1.0, bv3 = -1.0;
            int bi0 = 0, bi1 = 0, bi2 = 0, bi3 = 0;
            for (int j = 0; j < ncand; ++j) {
                double v = Ecand[j];
                const int m = cand[j];
                if (v > bv3) {
                    if (v > bv0) {
                        bv3 = bv2; bi3 = bi2; bv2 = bv1; bi2 = bi1; bv1 = bv0; bi1 = bi0;
                        bv0 = v; bi0 = m;
                    } else if (v > bv1) {
                        bv3 = bv2; bi3 = bi2; bv2 = bv1; bi2 = bi1;
                        bv1 = v; bi1 = m;
                    } else if (v > bv2) {
                        bv3 = bv2; bi3 = bi2;
                        bv2 = v; bi2 = m;
                    } else {
                        bv3 = v; bi3 = m;
                    }
                }
            }
            int sel[4] = {bi0, bi1, bi2, bi3};
            int* icnt = (int*)ws + WS_CNT_I;
            int* ilist = (int*)(ws + WS_LIST_F);
#pragma unroll
            for (int k = 0; k < 4; ++k) {
                const int e2 = sel[k];
                atomicAdd(&ws[WS_EACC + e2], Esh[e2]);
                atomicAdd(&ws[WS_CACC + e2], 1.0f);
                int pos = atomicAdd(&icnt[e2], 1);
                ilist[(e2 << 12) + pos] = (t << 2) | k;
            }
        }
        __syncthreads();
    }
}

// Expert-major contributions: contrib[t][k][d] (bf16 pairs packed in uint).
__launch_bounds__(256)
__global__ void expert_contrib_kernel(const float* __restrict__ U,
                                      const ushort* __restrict__ rbf,
                                      const float* __restrict__ ws,
                                      uint* __restrict__ contrib) {
    const int e = blockIdx.x;
    const int tid = threadIdx.x;
    const int cnt = ((const int*)ws)[WS_CNT_I + e];
    if ((int)blockIdx.y >= cnt) return;

    float usc[16];
#pragma unroll
    for (int b = 0; b < 16; ++b) usc[b] = ws[WS_USCALE + (e << 4) + b];

    const float* Up = U + (size_t)e * (D * B);
    float u0[16], u1[16];
#pragma unroll
    for (int qd = 0; qd < 4; ++qd) {
        float4 a = *(const float4*)(Up + (size_t)(2 * tid) * B + qd * 4);
        float4 b4 = *(const float4*)(Up + (size_t)(2 * tid + 1) * B + qd * 4);
        u0[qd * 4 + 0] = a.x * usc[qd * 4 + 0];
        u0[qd * 4 + 1] = a.y * usc[qd * 4 + 1];
        u0[qd * 4 + 2] = a.z * usc[qd * 4 + 2];
        u0[qd * 4 + 3] = a.w * usc[qd * 4 + 3];
        u1[qd * 4 + 0] = b4.x * usc[qd * 4 + 0];
        u1[qd * 4 + 1] = b4.y * usc[qd * 4 + 1];
        u1[qd * 4 + 2] = b4.z * usc[qd * 4 + 2];
        u1[qd * 4 + 3] = b4.w * usc[qd * 4 + 3];
    }

    const int* ilist = (const int*)(ws + WS_LIST_F) + (e << 12);
    int i = blockIdx.y;
    int pk = (i < cnt) ? ilist[i] : 0;
    while (i < cnt) {
        const int t = pk >> 2, k = pk & 3;
        const ushort* rp = rbf + (size_t)t * NC + (e << 4);
        union { ushort u[16]; uint4 q[2]; } R;
        R.q[0] = *(const uint4*)(rp);
        R.q[1] = *(const uint4*)(rp + 8);
        const int inext = i + 4;
        if (inext < cnt) pk = ilist[inext];
        float acc0 = 0.0f, acc1 = 0.0f;
#pragma unroll
        for (int b = 0; b < 16; ++b) {
            const float wv = bf2f(R.u[b]);
            acc0 = fmaf(u0[b], wv, acc0);
            acc1 = fmaf(u1[b], wv, acc1);
        }
        contrib[(size_t)((t << 2) + k) * 256 + tid] =
            (uint)f2bf(acc0) | ((uint)f2bf(acc1) << 16);
        i = inext;
    }
}

// blocks 0..1023: out = x + sum_k contrib  ; block 1024: finalize scalars
__launch_bounds__(256)
__global__ void combine_kernel(const float* __restrict__ x,
                               const uint* __restrict__ contrib,
                               const float* __restrict__ ws,
                               float* __restrict__ out) {
    if (blockIdx.x == 1024) {               // finalize
        const int m = threadIdx.x;
        if (m >= 128) return;
        float e = ws[WS_EACC + m] * (1.0f / (float)NTOK);
        float c = ws[WS_CACC + m] * (1.0f / (float)NTOK);
        float s = e;
#pragma unroll
        for (int off = 32; off > 0; off >>= 1) s += __shfl_down(s, off);
        __shared__ float sh[2];
        if ((m & 63) == 0) sh[m >> 6] = s;
        __syncthreads();
        float total = sh[0] + sh[1];
        float total_energy = fmaxf(total, 1e-12f);
        out[OUT_EPE + m] = e;
        out[OUT_RE + m] = e / total_energy;
        out[OUT_SR + m] = c;
        if (m == 0) {
            out[OUT_TE] = total_energy;
            float inv_n2 = 1.0f / ((float)NC * (float)NC);
            float sqrtD = sqrtf((float)D);
            float vpen = ws[WS_VSUM] * inv_n2 * sqrtD;
            float upen = ws[WS_USUM] * inv_n2 * sqrtD;
            out[OUT_VPEN] = vpen;
            out[OUT_UPEN] = upen;
            out[OUT_AUX] = 0.01f * vpen - total_energy;
        }
        return;
    }

    const int gid = blockIdx.x * 256 + threadIdx.x;
    const int t = gid >> 6;
    const int dq = (gid & 63) << 3;
    const uint4* cp = (const uint4*)contrib;

    float s[8];
    float4 x0 = *(const float4*)(x + (size_t)t * D + dq);
    float4 x1 = *(const float4*)(x + (size_t)t * D + dq + 4);
    s[0] = x0.x; s[1] = x0.y; s[2] = x0.z; s[3] = x0.w;
    s[4] = x1.x; s[5] = x1.y; s[6] = x1.z; s[7] = x1.w;
#pragma unroll
    for (int k = 0; k < KSEL; ++k) {
        uint4 cvec = cp[(size_t)((t << 2) + k) * 64 + (dq >> 3)];
        uint cc[4] = {cvec.x, cvec.y, cvec.z, cvec.w};
#pragma unroll
        for (int j = 0; j < 4; ++j) {
            s[2 * j]     += bf2f((ushort)(cc[j] & 0xffffu));
            s[2 * j + 1] += bf2f((ushort)(cc[j] >> 16));
        }
    }
    float* op = out + (size_t)t * D + dq;
    *(float4*)(op)     = make_float4(s[0], s[1], s[2], s[3]);
    *(float4*)(op + 4) = make_float4(s[4], s[5], s[6], s[7]);
}

extern "C" void kernel_launch(void* const* d_in, const int* in_sizes, int n_in,
                              void* d_out, int out_size, void* d_ws, size_t ws_size,
                              hipStream_t stream) {
    const float* x  = (const float*)d_in[0];
    const float* V  = (const float*)d_in[1];
    const float* U  = (const float*)d_in[2];
    const float* us = (const float*)d_in[3];
    float* out = (float*)d_out;
    float* ws  = (float*)d_ws;

    ushort* xh  = (ushort*)(ws + WS_XH_F);
    ushort* xl  = (ushort*)(ws + WS_XL_F);
    ushort* vht = (ushort*)(ws + WS_VHT_F);
    ushort* vlt = (ushort*)(ws + WS_VLT_F);
    ushort* uht = (ushort*)(ws + WS_UHT_F);
    ushort* ult = (ushort*)(ws + WS_ULT_F);
    ushort* rbf = (ushort*)(ws + WS_RBF_F);
    uint* contrib = (uint*)(ws + WS_XH_F);   // reuses xh..ult after mfma_fused

    prep_kernel<<<1570, 256, 0, stream>>>(x, V, U, us, xh, xl, vht, vlt, uht, ult, ws);
    mfma_fused<<<784, 256, 0, stream>>>(xh, xl, vht, vlt, uht, ult, ws, rbf);
    topk_kernel<<<NTOK / 4, 256, 0, stream>>>(ws);
    recheck_kernel<<<512, 256, 0, stream>>>(x, V, ws);
    expert_contrib_kernel<<<dim3(128, 4), 256, 0, stream>>>(U, rbf, ws, contrib);
    combine_kernel<<<1025, 256, 0, stream>>>(x, contrib, ws, out);
}

// Round 14
// 238.374 us; speedup vs baseline: 2.0229x; 1.0584x over previous
//
#include <hip/hip_runtime.h>
#include <math.h>

#define D 512
#define M 128
#define B 16
#define KSEL 4
#define NC 2048           // M*B
#define NTOK 4096         // 2*2048

typedef unsigned short ushort;
typedef unsigned int uint;
typedef unsigned long long u64;
typedef __attribute__((ext_vector_type(8))) short short8;   // 8 bf16 (4 VGPRs)
typedef __attribute__((ext_vector_type(4))) float floatx4;  // 4 fp32 acc

// ws layout (float indices)
#define WS_EACC   0       // [128]
#define WS_CACC   128     // [128]
#define WS_VSUM   256     // [1]
#define WS_USUM   257     // [1]
#define WS_CNT_I  258     // int counters [128] (inside zeroed first 512 floats)
#define WS_RCNT_I 386     // int recheck counter (inside zeroed head)
#define WS_VSCALE 512     // [2048] 1/||V col||
#define WS_USCALE 2560    // [2048] tanh(us)/||U col||
#define WS_E_F    4608    // [NTOK*M] fp32 energies, 2 MB
#define WS_RBF_F  528896  // R bf16 [NTOK][NC] (16 MB)
#define WS_XH_F   2626048 // xh bf16 [NTOK][D]; REUSED as contrib after mfma_fused
#define WS_XL_F   3674624 // xl bf16
#define WS_VHT_F  4723200 // VhT bf16 [NC][D]
#define WS_VLT_F  5247488
#define WS_UHT_F  5771776 // UhT bf16 [NC][D] (col = m*16+b)
#define WS_ULT_F  6296064
#define WS_LIST_F 6820352 // int [128][4096] per-expert token lists, packed (t<<2)|k
#define WS_RLIST_F 7344640 // int [4096] recheck token list
#define WS_RMASK_F 7348736 // u64 [4096][2] candidate ballots per deferred token
                           // end: 7365120 floats = 29.5 MB (ws >= 35.7 MB proven)

// out layout (floats)
#define OUT_TE   2097152
#define OUT_EPE  2097153
#define OUT_RE   2097281
#define OUT_SR   2097409
#define OUT_VPEN 2097537
#define OUT_UPEN 2097538
#define OUT_AUX  2097539

#define GLDS16(g, l) __builtin_amdgcn_global_load_lds(                        \
    (const __attribute__((address_space(1))) unsigned int*)(g),               \
    (__attribute__((address_space(3))) unsigned int*)(l), 16, 0, 0)

__device__ __forceinline__ ushort f2bf(float f) {   // RNE
    union { float f; uint u; } a; a.f = f;
    uint u = a.u;
    u += 0x7fffu + ((u >> 16) & 1u);
    return (ushort)(u >> 16);
}
__device__ __forceinline__ float bf2f(ushort h) {
    union { uint u; float f; } a; a.u = ((uint)h) << 16;
    return a.f;
}

// ---------------- fused prep: converts + scales + ws-zero (1570 blocks) ----
__launch_bounds__(256)
__global__ void prep_kernel(const float* __restrict__ x, const float* __restrict__ V,
                            const float* __restrict__ U, const float* __restrict__ us_in,
                            ushort* __restrict__ xh, ushort* __restrict__ xl,
                            ushort* __restrict__ vht, ushort* __restrict__ vlt,
                            ushort* __restrict__ uht, ushort* __restrict__ ult,
                            float* __restrict__ ws) {
    __shared__ float ts[64][65];
    const int bid = blockIdx.x;
    const int tid = threadIdx.x;

    if (bid < 1024) {                       // convert_x
        const int idx = (bid * 256 + tid) * 8;
        float4 v0 = *(const float4*)(x + idx);
        float4 v1 = *(const float4*)(x + idx + 4);
        float vv[8] = {v0.x, v0.y, v0.z, v0.w, v1.x, v1.y, v1.z, v1.w};
        union { ushort u[8]; uint4 q; } H, L;
#pragma unroll
        for (int j = 0; j < 8; ++j) {
            ushort h = f2bf(vv[j]);
            H.u[j] = h;
            L.u[j] = f2bf(vv[j] - bf2f(h));
        }
        *(uint4*)(xh + idx) = H.q;
        *(uint4*)(xl + idx) = L.q;
    } else if (bid < 1280) {                // convert_VT (64x64 tile transpose)
        const int vb = bid - 1024;
        const int col0 = (vb & 31) * 64;
        const int d0 = (vb >> 5) * 64;
#pragma unroll
        for (int i = 0; i < 16; ++i) {
            int idx = i * 256 + tid;
            int r = idx >> 6, c = idx & 63;
            ts[r][c] = V[(size_t)(d0 + r) * NC + col0 + c];
        }
        __syncthreads();
#pragma unroll
        for (int i = 0; i < 16; ++i) {
            int idx = i * 256 + tid;
            int c2 = idx >> 6, d2 = idx & 63;
            float v = ts[d2][c2];
            ushort h = f2bf(v);
            vht[(size_t)(col0 + c2) * D + d0 + d2] = h;
            vlt[(size_t)(col0 + c2) * D + d0 + d2] = f2bf(v - bf2f(h));
        }
    } else if (bid < 1408) {                // convert_UT (one expert per block)
        const int m = bid - 1280;
        float (*t2)[129] = (float (*)[129])ts;   // 16 x 129 view
        for (int d0 = 0; d0 < D; d0 += 128) {
            __syncthreads();
#pragma unroll
            for (int i = 0; i < 8; ++i) {
                int idx = i * 256 + tid;
                int d2 = idx >> 4, b2 = idx & 15;
                t2[b2][d2] = U[(size_t)m * (D * B) + (size_t)(d0 + d2) * B + b2];
            }
            __syncthreads();
#pragma unroll
            for (int i = 0; i < 8; ++i) {
                int idx = i * 256 + tid;
                int b3 = idx >> 7, d3 = idx & 127;
                float v = t2[b3][d3];
                ushort h = f2bf(v);
                uht[(size_t)((m << 4) + b3) * D + d0 + d3] = h;
                ult[(size_t)((m << 4) + b3) * D + d0 + d3] = f2bf(v - bf2f(h));
            }
        }
    } else {                                // scales + ws-head zero
        const int bx = bid - 1408;
        if (bx >= 160) {
            ws[(bx - 160) * 256 + tid] = 0.0f;
            return;
        }
        if (bx < 32) {
            const int c = bx * 64 + (tid & 63);
            const int dg = tid >> 6;
            float s = 0.0f;
            for (int d = dg; d < D; d += 4) {
                float v = V[(size_t)d * NC + c];
                s = fmaf(v, v, s);
            }
            float (*sh)[64] = (float (*)[64])ts;
            sh[dg][tid & 63] = s;
            __syncthreads();
            if (tid < 64) {
                float t = (sh[0][tid] + sh[1][tid]) + (sh[2][tid] + sh[3][tid]);
                ws[WS_VSCALE + bx * 64 + tid] = 1.0f / sqrtf(t);
            }
        } else {
            const int m = bx - 32;
            const float* p = U + (size_t)m * (D * B);
            float s = 0.0f;
            for (int i = tid; i < D * B; i += 256) {
                float v = p[i];
                s = fmaf(v, v, s);
            }
            float* sh2 = &ts[0][0];
            sh2[tid] = s;
            __syncthreads();
            if (tid < 16) {
                float t = 0.0f;
#pragma unroll
                for (int j = 0; j < 16; ++j) t += sh2[tid + (j << 4)];
                ws[WS_USCALE + (m << 4) + tid] = tanhf(us_in[(m << 4) + tid]) / sqrtf(t);
            }
        }
    }
}

// ---------------- fused MFMA: gemm tiles (blocks 0..511) + gram tiles (512..783)
__launch_bounds__(256)
__global__ void mfma_fused(const ushort* __restrict__ xh, const ushort* __restrict__ xl,
                           const ushort* __restrict__ vht, const ushort* __restrict__ vlt,
                           const ushort* __restrict__ uht, const ushort* __restrict__ ult,
                           float* __restrict__ ws, ushort* __restrict__ rbf) {
    __shared__ ushort smem[32768];   // 2 bufs x 4 tiles x (128 rows x 32 bf16)
    const int bid = blockIdx.x;
    const int tid = threadIdx.x, lane = tid & 63, w = tid >> 6;
    const int wr = w >> 1, wc = w & 1;
    const int r15 = lane & 15, q = lane >> 4;
    const int srl = lane >> 2;
    const int skq = (lane & 3) ^ ((lane >> 3) & 3);
    const int perm8 = (q ^ ((r15 >> 1) & 3)) * 8;

    const int is_gemm = bid < 512;
    const ushort* srcs[4];
    int rbase[4];
    int gi = 0, gj = 0, which = 0;
    if (is_gemm) {
        const int tokB = (bid & 31) * 128, colB = (bid >> 5) * 128;
        srcs[0] = xh; srcs[1] = xl; srcs[2] = vht; srcs[3] = vlt;
        rbase[0] = tokB; rbase[1] = tokB; rbase[2] = colB; rbase[3] = colB;
    } else {
        int t = bid - 512;
        which = t >= 136;
        if (which) t -= 136;
        int bi = 0, rem = 16;
        while (t >= rem) { t -= rem; --rem; ++bi; }
        gi = bi; gj = bi + t;
        const ushort* ht = which ? uht : vht;
        const ushort* lt = which ? ult : vlt;
        srcs[0] = ht; srcs[1] = lt; srcs[2] = ht; srcs[3] = lt;
        rbase[0] = gi * 128; rbase[1] = gi * 128; rbase[2] = gj * 128; rbase[3] = gj * 128;
    }

    floatx4 acc[4][4];
#pragma unroll
    for (int i = 0; i < 4; ++i)
#pragma unroll
        for (int j = 0; j < 4; ++j) acc[i][j] = (floatx4){0.f, 0.f, 0.f, 0.f};

    auto stage = [&](int buf, int c) {
        const int kb = c * 32 + skq * 8;
#pragma unroll
        for (int tI = 0; tI < 4; ++tI) {
            const ushort* s = srcs[tI] + (size_t)rbase[tI] * D + kb;
#pragma unroll
            for (int sub = 0; sub < 2; ++sub) {
                const int row16 = w * 32 + sub * 16;
                GLDS16(s + (size_t)(row16 + srl) * D,
                       &smem[buf * 16384 + tI * 4096 + row16 * 32]);
            }
        }
    };

    stage(0, 0);
    for (int c = 0; c < 16; ++c) {
        __syncthreads();
        if (c < 15) stage((c + 1) & 1, c + 1);
        const ushort* bp = &smem[(c & 1) * 16384];
        short8 ah[4], al[4], bh[4], bl[4];
#pragma unroll
        for (int s = 0; s < 4; ++s) {
            const int ra = (wr * 64 + s * 16 + r15) * 32 + perm8;
            ah[s] = *(const short8*)&bp[ra];
            al[s] = *(const short8*)&bp[4096 + ra];
            const int rb = (wc * 64 + s * 16 + r15) * 32 + perm8;
            bh[s] = *(const short8*)&bp[8192 + rb];
            bl[s] = *(const short8*)&bp[12288 + rb];
        }
#pragma unroll
        for (int st = 0; st < 4; ++st)
#pragma unroll
            for (int sc = 0; sc < 4; ++sc) {
                acc[st][sc] = __builtin_amdgcn_mfma_f32_16x16x32_bf16(ah[st], bh[sc], acc[st][sc], 0, 0, 0);
                acc[st][sc] = __builtin_amdgcn_mfma_f32_16x16x32_bf16(ah[st], bl[sc], acc[st][sc], 0, 0, 0);
                acc[st][sc] = __builtin_amdgcn_mfma_f32_16x16x32_bf16(al[st], bh[sc], acc[st][sc], 0, 0, 0);
            }
    }

    if (is_gemm) {
        const int tok0 = (bid & 31) * 128 + wr * 64, col0 = (bid >> 5) * 128 + wc * 64;
#pragma unroll
        for (int sc = 0; sc < 4; ++sc) {
            const int colg = col0 + sc * 16 + r15;
            const float vs = ws[WS_VSCALE + colg];
            const int ex = colg >> 4;
#pragma unroll
            for (int st = 0; st < 4; ++st) {
                const int rowb = tok0 + st * 16 + q * 4;
                float r0 = acc[st][sc][0] * vs;
                float r1 = acc[st][sc][1] * vs;
                float r2 = acc[st][sc][2] * vs;
                float r3 = acc[st][sc][3] * vs;
                rbf[(size_t)(rowb + 0) * NC + colg] = f2bf(r0);
                rbf[(size_t)(rowb + 1) * NC + colg] = f2bf(r1);
                rbf[(size_t)(rowb + 2) * NC + colg] = f2bf(r2);
                rbf[(size_t)(rowb + 3) * NC + colg] = f2bf(r3);
                float e0 = r0 * r0, e1 = r1 * r1, e2 = r2 * r2, e3 = r3 * r3;
#pragma unroll
                for (int mk = 1; mk < 16; mk <<= 1) {
                    e0 += __shfl_xor(e0, mk);
                    e1 += __shfl_xor(e1, mk);
                    e2 += __shfl_xor(e2, mk);
                    e3 += __shfl_xor(e3, mk);
                }
                if (r15 == 0) {
                    float* ep = ws + WS_E_F + (size_t)rowb * M + ex;
                    ep[0] = e0; ep[M] = e1; ep[2 * M] = e2; ep[3 * M] = e3;
                }
            }
        }
    } else {
        const float* scl = ws + (which ? WS_USCALE : WS_VSCALE);
        float* sum_out = ws + (which ? WS_USUM : WS_VSUM);
        float local = 0.0f;
#pragma unroll
        for (int sc = 0; sc < 4; ++sc) {
            const int colg = gj * 128 + wc * 64 + sc * 16 + r15;
            const float scj = scl[colg];
#pragma unroll
            for (int st = 0; st < 4; ++st) {
#pragma unroll
                for (int reg = 0; reg < 4; ++reg) {
                    const int rowg = gi * 128 + wr * 64 + st * 16 + q * 4 + reg;
                    float g = acc[st][sc][reg] * scl[rowg] * scj;
                    if (rowg == colg) g -= 1.0f;
                    local += fabsf(g);
                }
            }
        }
        if (gi < gj) local *= 2.0f;
#pragma unroll
        for (int mk = 1; mk < 64; mk <<= 1) local += __shfl_xor(local, mk);
        __shared__ float red[4];
        if (lane == 0) red[w] = local;
        __syncthreads();
        if (tid == 0) atomicAdd(sum_out, (red[0] + red[1]) + (red[2] + red[3]));
    }
}

// Wave-per-token top-4 with robustness gate; deferred tokens also store their
// candidate ballots (experts with E >= e4*(1-2e-3)) — free here, saves the
// recheck kernel two serial 128-iter scans.
__launch_bounds__(256)
__global__ void topk_kernel(float* __restrict__ ws) {
    const int tid = threadIdx.x, lane = tid & 63, w = tid >> 6;
    const int t = blockIdx.x * 4 + w;
    int* icnt = (int*)ws + WS_CNT_I;
    int* ilist = (int*)(ws + WS_LIST_F);

    const float2 ev = *(const float2*)(ws + WS_E_F + (size_t)t * M + lane * 2);
    const uint i0 = (uint)(lane * 2), i1 = i0 + 1;
    u64 k0 = ((u64)__float_as_uint(ev.x) << 32) | (uint)(~i0);
    u64 k1 = ((u64)__float_as_uint(ev.y) << 32) | (uint)(~i1);
    u64 s0 = k0 > k1 ? k0 : k1;
    u64 s1 = k0 > k1 ? k1 : k0;
    u64 s2 = 0, s3 = 0;

#pragma unroll
    for (int mk = 1; mk < 64; mk <<= 1) {
        u64 o0 = __shfl_xor(s0, mk);
        u64 o1 = __shfl_xor(s1, mk);
        u64 o2 = __shfl_xor(s2, mk);
        u64 o3 = __shfl_xor(s3, mk);
        u64 c0 = s0 > o3 ? s0 : o3;
        u64 c1 = s1 > o2 ? s1 : o2;
        u64 c2 = s2 > o1 ? s2 : o1;
        u64 c3 = s3 > o0 ? s3 : o0;
        u64 d0 = c0 > c2 ? c0 : c2, d2 = c0 > c2 ? c2 : c0;
        u64 d1 = c1 > c3 ? c1 : c3, d3 = c1 > c3 ? c3 : c1;
        s0 = d0 > d1 ? d0 : d1; s1 = d0 > d1 ? d1 : d0;
        s2 = d2 > d3 ? d2 : d3; s3 = d2 > d3 ? d3 : d2;
    }

    u64 m0 = (k0 == s0 || k0 == s1 || k0 == s2 || k0 == s3) ? 0 : k0;
    u64 m1 = (k1 == s0 || k1 == s1 || k1 == s2 || k1 == s3) ? 0 : k1;
    u64 mx = m0 > m1 ? m0 : m1;
#pragma unroll
    for (int mk = 1; mk < 64; mk <<= 1) {
        u64 om = __shfl_xor(mx, mk);
        if (om > mx) mx = om;
    }

    const float e4 = __uint_as_float((uint)(s3 >> 32));
    const float e5 = __uint_as_float((uint)(mx >> 32));
    const bool robust = (e4 - e5) > 1e-3f * e4;

    if (robust) {
        if (lane < 4) {
            u64 key = (lane == 0) ? s0 : (lane == 1) ? s1 : (lane == 2) ? s2 : s3;
            const int e = (int)(~(uint)key);
            const float val = __uint_as_float((uint)(key >> 32));
            atomicAdd(&ws[WS_EACC + e], val);
            atomicAdd(&ws[WS_CACC + e], 1.0f);
            int pos = atomicAdd(&icnt[e], 1);
            ilist[(e << 12) + pos] = (t << 2) | lane;
        }
    } else {
        const float thresh = e4 - 2e-3f * e4;
        u64 ball0 = __ballot(ev.x >= thresh);   // even experts 2*lane
        u64 ball1 = __ballot(ev.y >= thresh);   // odd experts 2*lane+1
        if (lane == 0) {
            int* rc = (int*)ws + WS_RCNT_I;
            int p = atomicAdd(rc, 1);
            ((int*)(ws + WS_RLIST_F))[p] = t;
            u64* mp = (u64*)(ws + WS_RMASK_F) + 2 * (size_t)p;
            mp[0] = ball0;
            mp[1] = ball1;
        }
    }
}

// Candidate-restricted fp64 recheck. Round-14: candidate decode from the
// precomputed ballots (parallel popcount ranking — no serial scans, no full
// E-row staging). Dot: 8 independent fp64 accumulators. Grid 512.
__launch_bounds__(256)
__global__ void recheck_kernel(const float* __restrict__ x,
                               const float* __restrict__ V,
                               float* __restrict__ ws) {
    const int rcnt = ((const int*)ws)[WS_RCNT_I];
    __shared__ float xs[512];
    __shared__ int cand[16];
    __shared__ int ncand_sh;
    __shared__ double Ecand[16];
    const int tid = threadIdx.x;

    for (int ri = blockIdx.x; ri < rcnt; ri += gridDim.x) {
        const int t = ((const int*)(ws + WS_RLIST_F))[ri];
        const u64* mp = (const u64*)(ws + WS_RMASK_F) + 2 * (size_t)ri;

        if (tid < 128) {
            *(float4*)&xs[tid * 4] = *(const float4*)(x + (size_t)t * D + tid * 4);
            const u64 b0 = mp[0], b1 = mp[1];
            if (tid == 0) {
                int nc = (int)(__popcll(b0) + __popcll(b1));
                ncand_sh = nc < 16 ? nc : 16;
            }
            // expert tid: rank = #candidates with lower index (ascending order)
            const int e = tid, L = e >> 1;
            const u64 mlt = (1ULL << L) - 1;   // bits strictly below L (L=0 -> 0)
            const int bit = (int)((((e & 1) ? b1 : b0) >> L) & 1);
            if (bit) {
                const u64 m0s = (e & 1) ? (mlt | (1ULL << L)) : mlt;
                int rank = (int)__popcll(b0 & m0s) + (int)__popcll(b1 & mlt);
                if (rank < 16) cand[rank] = e;
            }
        }
        __syncthreads();
        const int ncand = ncand_sh;

        const int ci = tid >> 4, b = tid & 15;
        int c = 0;
        double pa[8] = {0, 0, 0, 0, 0, 0, 0, 0};
        if (ci < ncand) {
            c = (cand[ci] << 4) + b;
            const float* vp = V + c;
            for (int d = 0; d < D; d += 8) {
#pragma unroll
                for (int j = 0; j < 8; ++j)
                    pa[j] += (double)xs[d + j] * (double)vp[(size_t)(d + j) * NC];
            }
        }
        double e = ((pa[0] + pa[1]) + (pa[2] + pa[3])) +
                   ((pa[4] + pa[5]) + (pa[6] + pa[7]));
        double sc = (ci < ncand) ? (double)ws[WS_VSCALE + c] : 0.0;
        e = (e * e) * (sc * sc);
#pragma unroll
        for (int mk = 1; mk < 16; mk <<= 1) e += __shfl_xor(e, mk);
        if (ci < ncand && b == 0 && ci < 16) Ecand[ci] = e;
        __syncthreads();

        if (tid == 0) {
            double bv0 = -1.0, bv1 = -1.0, bv2 = -1.0, bv3 = -1.0;
            int bi0 = 0, bi1 = 0, bi2 = 0, bi3 = 0;
            for (int j = 0; j < ncand; ++j) {
                double v = Ecand[j];
                const int m = cand[j];
                if (v > bv3) {
                    if (v > bv0) {
                        bv3 = bv2; bi3 = bi2; bv2 = bv1; bi2 = bi1; bv1 = bv0; bi1 = bi0;
                        bv0 = v; bi0 = m;
                    } else if (v > bv1) {
                        bv3 = bv2; bi3 = bi2; bv2 = bv1; bi2 = bi1;
                        bv1 = v; bi1 = m;
                    } else if (v > bv2) {
                        bv3 = bv2; bi3 = bi2;
                        bv2 = v; bi2 = m;
                    } else {
                        bv3 = v; bi3 = m;
                    }
                }
            }
            int sel[4] = {bi0, bi1, bi2, bi3};
            int* icnt = (int*)ws + WS_CNT_I;
            int* ilist = (int*)(ws + WS_LIST_F);
#pragma unroll
            for (int k = 0; k < 4; ++k) {
                const int e2 = sel[k];
                atomicAdd(&ws[WS_EACC + e2], ws[WS_E_F + (size_t)t * M + e2]);
                atomicAdd(&ws[WS_CACC + e2], 1.0f);
                int pos = atomicAdd(&icnt[e2], 1);
                ilist[(e2 << 12) + pos] = (t << 2) | k;
            }
        }
        __syncthreads();
    }
}

// Expert-major contributions: contrib[t][k][d] (bf16 pairs packed in uint).
__launch_bounds__(256)
__global__ void expert_contrib_kernel(const float* __restrict__ U,
                                      const ushort* __restrict__ rbf,
                                      const float* __restrict__ ws,
                                      uint* __restrict__ contrib) {
    const int e = blockIdx.x;
    const int tid = threadIdx.x;
    const int cnt = ((const int*)ws)[WS_CNT_I + e];
    if ((int)blockIdx.y >= cnt) return;

    float usc[16];
#pragma unroll
    for (int b = 0; b < 16; ++b) usc[b] = ws[WS_USCALE + (e << 4) + b];

    const float* Up = U + (size_t)e * (D * B);
    float u0[16], u1[16];
#pragma unroll
    for (int qd = 0; qd < 4; ++qd) {
        float4 a = *(const float4*)(Up + (size_t)(2 * tid) * B + qd * 4);
        float4 b4 = *(const float4*)(Up + (size_t)(2 * tid + 1) * B + qd * 4);
        u0[qd * 4 + 0] = a.x * usc[qd * 4 + 0];
        u0[qd * 4 + 1] = a.y * usc[qd * 4 + 1];
        u0[qd * 4 + 2] = a.z * usc[qd * 4 + 2];
        u0[qd * 4 + 3] = a.w * usc[qd * 4 + 3];
        u1[qd * 4 + 0] = b4.x * usc[qd * 4 + 0];
        u1[qd * 4 + 1] = b4.y * usc[qd * 4 + 1];
        u1[qd * 4 + 2] = b4.z * usc[qd * 4 + 2];
        u1[qd * 4 + 3] = b4.w * usc[qd * 4 + 3];
    }

    const int* ilist = (const int*)(ws + WS_LIST_F) + (e << 12);
    int i = blockIdx.y;
    int pk = (i < cnt) ? ilist[i] : 0;
    while (i < cnt) {
        const int t = pk >> 2, k = pk & 3;
        const ushort* rp = rbf + (size_t)t * NC + (e << 4);
        union { ushort u[16]; uint4 q[2]; } R;
        R.q[0] = *(const uint4*)(rp);
        R.q[1] = *(const uint4*)(rp + 8);
        const int inext = i + 4;
        if (inext < cnt) pk = ilist[inext];
        float acc0 = 0.0f, acc1 = 0.0f;
#pragma unroll
        for (int b = 0; b < 16; ++b) {
            const float wv = bf2f(R.u[b]);
            acc0 = fmaf(u0[b], wv, acc0);
            acc1 = fmaf(u1[b], wv, acc1);
        }
        contrib[(size_t)((t << 2) + k) * 256 + tid] =
            (uint)f2bf(acc0) | ((uint)f2bf(acc1) << 16);
        i = inext;
    }
}

// blocks 0..1023: out = x + sum_k contrib  ; block 1024: finalize scalars
__launch_bounds__(256)
__global__ void combine_kernel(const float* __restrict__ x,
                               const uint* __restrict__ contrib,
                               const float* __restrict__ ws,
                               float* __restrict__ out) {
    if (blockIdx.x == 1024) {               // finalize
        const int m = threadIdx.x;
        if (m >= 128) return;
        float e = ws[WS_EACC + m] * (1.0f / (float)NTOK);
        float c = ws[WS_CACC + m] * (1.0f / (float)NTOK);
        float s = e;
#pragma unroll
        for (int off = 32; off > 0; off >>= 1) s += __shfl_down(s, off);
        __shared__ float sh[2];
        if ((m & 63) == 0) sh[m >> 6] = s;
        __syncthreads();
        float total = sh[0] + sh[1];
        float total_energy = fmaxf(total, 1e-12f);
        out[OUT_EPE + m] = e;
        out[OUT_RE + m] = e / total_energy;
        out[OUT_SR + m] = c;
        if (m == 0) {
            out[OUT_TE] = total_energy;
            float inv_n2 = 1.0f / ((float)NC * (float)NC);
            float sqrtD = sqrtf((float)D);
            float vpen = ws[WS_VSUM] * inv_n2 * sqrtD;
            float upen = ws[WS_USUM] * inv_n2 * sqrtD;
            out[OUT_VPEN] = vpen;
            out[OUT_UPEN] = upen;
            out[OUT_AUX] = 0.01f * vpen - total_energy;
        }
        return;
    }

    const int gid = blockIdx.x * 256 + threadIdx.x;
    const int t = gid >> 6;
    const int dq = (gid & 63) << 3;
    const uint4* cp = (const uint4*)contrib;

    float s[8];
    float4 x0 = *(const float4*)(x + (size_t)t * D + dq);
    float4 x1 = *(const float4*)(x + (size_t)t * D + dq + 4);
    s[0] = x0.x; s[1] = x0.y; s[2] = x0.z; s[3] = x0.w;
    s[4] = x1.x; s[5] = x1.y; s[6] = x1.z; s[7] = x1.w;
#pragma unroll
    for (int k = 0; k < KSEL; ++k) {
        uint4 cvec = cp[(size_t)((t << 2) + k) * 64 + (dq >> 3)];
        uint cc[4] = {cvec.x, cvec.y, cvec.z, cvec.w};
#pragma unroll
        for (int j = 0; j < 4; ++j) {
            s[2 * j]     += bf2f((ushort)(cc[j] & 0xffffu));
            s[2 * j + 1] += bf2f((ushort)(cc[j] >> 16));
        }
    }
    float* op = out + (size_t)t * D + dq;
    *(float4*)(op)     = make_float4(s[0], s[1], s[2], s[3]);
    *(float4*)(op + 4) = make_float4(s[4], s[5], s[6], s[7]);
}

extern "C" void kernel_launch(void* const* d_in, const int* in_sizes, int n_in,
                              void* d_out, int out_size, void* d_ws, size_t ws_size,
                              hipStream_t stream) {
    const float* x  = (const float*)d_in[0];
    const float* V  = (const float*)d_in[1];
    const float* U  = (const float*)d_in[2];
    const float* us = (const float*)d_in[3];
    float* out = (float*)d_out;
    float* ws  = (float*)d_ws;

    ushort* xh  = (ushort*)(ws + WS_XH_F);
    ushort* xl  = (ushort*)(ws + WS_XL_F);
    ushort* vht = (ushort*)(ws + WS_VHT_F);
    ushort* vlt = (ushort*)(ws + WS_VLT_F);
    ushort* uht = (ushort*)(ws + WS_UHT_F);
    ushort* ult = (ushort*)(ws + WS_ULT_F);
    ushort* rbf = (ushort*)(ws + WS_RBF_F);
    uint* contrib = (uint*)(ws + WS_XH_F);   // reuses xh..ult after mfma_fused

    prep_kernel<<<1570, 256, 0, stream>>>(x, V, U, us, xh, xl, vht, vlt, uht, ult, ws);
    mfma_fused<<<784, 256, 0, stream>>>(xh, xl, vht, vlt, uht, ult, ws, rbf);
    topk_kernel<<<NTOK / 4, 256, 0, stream>>>(ws);
    recheck_kernel<<<512, 256, 0, stream>>>(x, V, ws);
    expert_contrib_kernel<<<dim3(128, 4), 256, 0, stream>>>(U, rbf, ws, contrib);
    combine_kernel<<<1025, 256, 0, stream>>>(x, contrib, ws, out);
}